// Round 1
// baseline (310.067 us; speedup 1.0000x reference)
//
#include <hip/hip_runtime.h>

typedef _Float16 half_t;
typedef _Float16 half4_t __attribute__((ext_vector_type(4)));
typedef _Float16 half8_t __attribute__((ext_vector_type(8)));
typedef float f32x4 __attribute__((ext_vector_type(4)));
typedef float float4_t __attribute__((ext_vector_type(4)));

#define NB 16
#define NC 512
#define NT 1024
#define NHEAD 8
#define DH 64

// ---------------- workspace layout (bytes) ----------------
#define OFF_W16  ((size_t)0)                                  // qkv_w fp16 [1536][512]
#define OFF_PW16 (OFF_W16  + (size_t)1536*512*2)              // proj_w fp16 [512][512]
#define OFF_XNT  (OFF_PW16 + (size_t)512*512*2)               // xnT fp16 [16][1024][512]
#define OFF_QKV  (OFF_XNT  + (size_t)16*1024*512*2)           // qkv fp16 [16][1536][1024]
#define OFF_AT   (OFF_QKV  + (size_t)16*1536*1024*2)          // aT  fp16 [16][1024][512]
#define OFF_STAT (OFF_AT   + (size_t)16*1024*512*2)           // stats f32 [16][32][2]

// ---------------- K0: weights fp32 -> fp16 ----------------
__global__ void k_convert_w(const float* __restrict__ qkv_w, const float* __restrict__ proj_w,
                            half_t* __restrict__ w16, half_t* __restrict__ pw16) {
    int i = (blockIdx.x * 256 + threadIdx.x) * 4;
    const int NQ = 1536 * 512;
    if (i < NQ) {
        float4_t v = *(const float4_t*)(qkv_w + i);
        half4_t h; for (int j = 0; j < 4; j++) h[j] = (half_t)v[j];
        *(half4_t*)(w16 + i) = h;
    } else {
        int k = i - NQ;
        float4_t v = *(const float4_t*)(proj_w + k);
        half4_t h; for (int j = 0; j < 4; j++) h[j] = (half_t)v[j];
        *(half4_t*)(pw16 + k) = h;
    }
}

// ---------------- K1: per-(b,group) mean / rsigma ----------------
__global__ void k_gn_stats(const float* __restrict__ x, float* __restrict__ stats) {
    int bg = blockIdx.x;                       // b*32+g ; group = 16 ch * 1024 = 16384 contiguous floats
    const float* p = x + (size_t)bg * 16384;
    float s = 0.f, sq = 0.f;
    for (int i = threadIdx.x; i < 4096; i += 256) {
        float4_t v = *(const float4_t*)(p + i * 4);
        for (int j = 0; j < 4; j++) { s += v[j]; sq += v[j] * v[j]; }
    }
    for (int m = 1; m < 64; m <<= 1) { s += __shfl_xor(s, m, 64); sq += __shfl_xor(sq, m, 64); }
    __shared__ float red[2][4];
    int wid = threadIdx.x >> 6;
    if ((threadIdx.x & 63) == 0) { red[0][wid] = s; red[1][wid] = sq; }
    __syncthreads();
    if (threadIdx.x == 0) {
        s  = red[0][0] + red[0][1] + red[0][2] + red[0][3];
        sq = red[1][0] + red[1][1] + red[1][2] + red[1][3];
        float mean = s * (1.f / 16384.f);
        float var  = sq * (1.f / 16384.f) - mean * mean;
        stats[bg * 2]     = mean;
        stats[bg * 2 + 1] = rsqrtf(var + 1e-5f);
    }
}

// ---------------- K2: normalize + scale/bias + fp16 + transpose -> xnT[b][t][c] ----------------
__global__ void k_gn_apply_t(const float* __restrict__ x, const float* __restrict__ stats,
                             const float* __restrict__ scale, const float* __restrict__ bias,
                             half_t* __restrict__ xnT) {
    int bx = blockIdx.x;            // 16 * 8 * 16
    int b = bx >> 7;
    int r = bx & 127;
    int c0 = (r >> 4) * 64;
    int t0 = (r & 15) * 64;
    __shared__ half_t lds[64][72];
    int ci = threadIdx.x >> 4;          // 0..15
    int tj = (threadIdx.x & 15) * 4;
    for (int p = 0; p < 4; p++) {
        int c = c0 + ci + p * 16;
        float mean = stats[(b * 32 + (c >> 4)) * 2];
        float rsig = stats[(b * 32 + (c >> 4)) * 2 + 1];
        float sc = scale[c] * rsig;
        float bs = bias[c] - mean * sc;
        float4_t v = *(const float4_t*)(x + ((size_t)(b * 512 + c)) * 1024 + t0 + tj);
        half4_t hx;
        for (int j = 0; j < 4; j++) hx[j] = (half_t)(v[j] * sc + bs);
        *(half4_t*)(&lds[ci + p * 16][tj]) = hx;
    }
    __syncthreads();
    int cj = (threadIdx.x & 7) * 8;
    int ti = threadIdx.x >> 3;          // 0..31
    for (int p = 0; p < 2; p++) {
        int t = ti + p * 32;
        half8_t h;
        for (int j = 0; j < 8; j++) h[j] = lds[cj + j][t];
        *(half8_t*)(xnT + ((size_t)(b * 1024 + t0 + t)) * 512 + c0 + cj) = h;
    }
}

// ---------------- K3: QKV GEMM  (M=t 128, N=o 128, K=c 512) ----------------
__global__ __launch_bounds__(256) void k_qkv_gemm(const half_t* __restrict__ xnT,
                                                  const half_t* __restrict__ w16,
                                                  const float* __restrict__ qkv_b,
                                                  half_t* __restrict__ qkv) {
    int bx = blockIdx.x;            // 16 * 8 * 12
    int b = bx / 96;
    int r = bx % 96;
    int t0 = (r / 12) * 128;
    int o0 = (r % 12) * 128;
    __shared__ half_t lA[128][72];
    __shared__ half_t lB[128][72];
    int tid = threadIdx.x;
    int lane = tid & 63, wid = tid >> 6;
    int wr = wid >> 1, wc = wid & 1;
    int l15 = lane & 15, l4 = lane >> 4;
    f32x4 acc[4][4] = {};
    const int rowA0 = tid >> 3;          // 0..31
    const int col8 = (tid & 7) * 8;
    for (int kk = 0; kk < 512; kk += 64) {
        for (int p = 0; p < 4; p++) {
            int row = rowA0 + p * 32;
            *(half8_t*)(&lA[row][col8]) =
                *(const half8_t*)(xnT + ((size_t)(b * 1024) + t0 + row) * 512 + kk + col8);
            *(half8_t*)(&lB[row][col8]) =
                *(const half8_t*)(w16 + (size_t)(o0 + row) * 512 + kk + col8);
        }
        __syncthreads();
        for (int ks = 0; ks < 2; ks++) {
            int colk = ks * 32 + l4 * 8;
            half8_t a[4], bb[4];
            for (int mi = 0; mi < 4; mi++) a[mi]  = *(const half8_t*)(&lA[wr * 64 + mi * 16 + l15][colk]);
            for (int ni = 0; ni < 4; ni++) bb[ni] = *(const half8_t*)(&lB[wc * 64 + ni * 16 + l15][colk]);
            for (int mi = 0; mi < 4; mi++)
                for (int ni = 0; ni < 4; ni++)
                    acc[mi][ni] = __builtin_amdgcn_mfma_f32_16x16x32_f16(a[mi], bb[ni], acc[mi][ni], 0, 0, 0);
        }
        __syncthreads();
    }
    for (int ni = 0; ni < 4; ni++) {
        int o = o0 + wc * 64 + ni * 16 + l15;
        float bias = qkv_b[o];
        for (int mi = 0; mi < 4; mi++) {
            int t = t0 + wr * 64 + mi * 16 + l4 * 4;
            half4_t h;
            for (int j = 0; j < 4; j++) h[j] = (half_t)(acc[mi][ni][j] + bias);
            *(half4_t*)(qkv + ((size_t)(b * 1536) + o) * 1024 + t) = h;
        }
    }
}

// ---------------- K4: flash attention per (b,h,t-tile of 64) ----------------
__global__ __launch_bounds__(256) void k_attn(const half_t* __restrict__ qkv, half_t* __restrict__ aT) {
    int bx = blockIdx.x;            // 128 * 16
    int bh = bx >> 4;
    int t0 = (bx & 15) * 64;
    int b = bh >> 3, h = bh & 7;
    const half_t* qb = qkv + ((size_t)(b * 1536) + h * 64) * 1024;
    const half_t* kb = qb + (size_t)512 * 1024;
    const half_t* vb = qb + (size_t)1024 * 1024;

    __shared__ half_t lqT[64][72];     // [t][d]
    __shared__ half_t lkT[64][72];     // [s][d]
    __shared__ half_t lv [64][72];     // [d][s]
    __shared__ half_t lp [4][16][72];  // per wave: [t][s]

    int tid = threadIdx.x;
    int lane = tid & 63, w = tid >> 6;
    int l15 = lane & 15, l4 = lane >> 4;

    // stage q transposed (once)
    {
        int d = tid & 63, tc = tid >> 6;
        for (int hf = 0; hf < 2; hf++) {
            half8_t v = *(const half8_t*)(qb + (size_t)d * 1024 + t0 + tc * 16 + hf * 8);
            for (int j = 0; j < 8; j++) lqT[tc * 16 + hf * 8 + j][d] = v[j];
        }
    }
    __syncthreads();
    half8_t aq[2];
    for (int ks = 0; ks < 2; ks++)
        aq[ks] = *(const half8_t*)(&lqT[w * 16 + l15][ks * 32 + l4 * 8]);

    f32x4 oacc[4] = {};
    float m_[4], l_[4];
    for (int i = 0; i < 4; i++) { m_[i] = -1e30f; l_[i] = 0.f; }

    for (int it = 0; it < 16; it++) {
        int s0 = it * 64;
        __syncthreads();   // protect lkT/lv from previous iteration's readers
        {
            int d = tid & 63, sc = tid >> 6;
            for (int hf = 0; hf < 2; hf++) {
                half8_t kv = *(const half8_t*)(kb + (size_t)d * 1024 + s0 + sc * 16 + hf * 8);
                for (int j = 0; j < 8; j++) lkT[sc * 16 + hf * 8 + j][d] = kv[j];
                half8_t vv = *(const half8_t*)(vb + (size_t)d * 1024 + s0 + sc * 16 + hf * 8);
                *(half8_t*)(&lv[d][sc * 16 + hf * 8]) = vv;
            }
        }
        __syncthreads();
        // S = (q^T k) * 1/8
        f32x4 sacc[4] = {};
        for (int ks = 0; ks < 2; ks++) {
            int colk = ks * 32 + l4 * 8;
            for (int ni = 0; ni < 4; ni++) {
                half8_t bk = *(const half8_t*)(&lkT[ni * 16 + l15][colk]);
                sacc[ni] = __builtin_amdgcn_mfma_f32_16x16x32_f16(aq[ks], bk, sacc[ni], 0, 0, 0);
            }
        }
        for (int ni = 0; ni < 4; ni++)
            for (int i = 0; i < 4; i++) sacc[ni][i] *= 0.125f;
        // online softmax (wave-parallel; lane group l4 owns rows 4*l4+i)
        float fR[4];
        for (int i = 0; i < 4; i++) {
            float tm = fmaxf(fmaxf(sacc[0][i], sacc[1][i]), fmaxf(sacc[2][i], sacc[3][i]));
            for (int msk = 1; msk < 16; msk <<= 1) tm = fmaxf(tm, __shfl_xor(tm, msk, 64));
            float nm = fmaxf(m_[i], tm);
            float f = __expf(m_[i] - nm);
            float ps = 0.f;
            int trow = l4 * 4 + i;
            for (int ni = 0; ni < 4; ni++) {
                float p = __expf(sacc[ni][i] - nm);
                ps += p;
                lp[w][trow][ni * 16 + l15] = (half_t)p;
            }
            for (int msk = 1; msk < 16; msk <<= 1) ps += __shfl_xor(ps, msk, 64);
            l_[i] = l_[i] * f + ps;
            m_[i] = nm;
            fR[i] = f;
        }
        // rescale O (col t = l15): fetch factor from owning lane group
        int src = (l15 >> 2) * 16;
        float f0 = __shfl(fR[0], src, 64), f1 = __shfl(fR[1], src, 64);
        float f2 = __shfl(fR[2], src, 64), f3 = __shfl(fR[3], src, 64);
        int sel = l15 & 3;
        float ft = sel == 0 ? f0 : sel == 1 ? f1 : sel == 2 ? f2 : f3;
        for (int mi = 0; mi < 4; mi++)
            for (int i = 0; i < 4; i++) oacc[mi][i] *= ft;
        // O += V P^T   (A = v[d][s] natural, B = P[t][s] from lp)
        for (int ks = 0; ks < 2; ks++) {
            int colk = ks * 32 + l4 * 8;
            half8_t bp = *(const half8_t*)(&lp[w][l15][colk]);
            for (int mi = 0; mi < 4; mi++) {
                half8_t av = *(const half8_t*)(&lv[mi * 16 + l15][colk]);
                oacc[mi] = __builtin_amdgcn_mfma_f32_16x16x32_f16(av, bp, oacc[mi], 0, 0, 0);
            }
        }
    }
    // O /= l ; store aT[b][t][h*64+d]
    int src = (l15 >> 2) * 16;
    float l0 = __shfl(l_[0], src, 64), l1 = __shfl(l_[1], src, 64);
    float l2 = __shfl(l_[2], src, 64), l3 = __shfl(l_[3], src, 64);
    int sel = l15 & 3;
    float lt = sel == 0 ? l0 : sel == 1 ? l1 : sel == 2 ? l2 : l3;
    float linv = 1.0f / lt;
    int t = t0 + w * 16 + l15;
    for (int mi = 0; mi < 4; mi++) {
        half4_t hv;
        for (int i = 0; i < 4; i++) hv[i] = (half_t)(oacc[mi][i] * linv);
        *(half4_t*)(aT + ((size_t)(b * 1024) + t) * 512 + h * 64 + mi * 16 + l4 * 4) = hv;
    }
}

// ---------------- K5: proj GEMM + bias + residual  (M=t, N=o, K=c) ----------------
__global__ __launch_bounds__(256) void k_proj_gemm(const half_t* __restrict__ aT,
                                                   const half_t* __restrict__ pw16,
                                                   const float* __restrict__ proj_b,
                                                   const float* __restrict__ x,
                                                   float* __restrict__ out) {
    int bx = blockIdx.x;            // 16 * 8 * 4
    int b = bx / 32;
    int r = bx % 32;
    int t0 = (r / 4) * 128;
    int o0 = (r % 4) * 128;
    __shared__ half_t lA[128][72];
    __shared__ half_t lB[128][72];
    int tid = threadIdx.x;
    int lane = tid & 63, wid = tid >> 6;
    int wr = wid >> 1, wc = wid & 1;
    int l15 = lane & 15, l4 = lane >> 4;
    f32x4 acc[4][4] = {};
    const int rowA0 = tid >> 3;
    const int col8 = (tid & 7) * 8;
    for (int kk = 0; kk < 512; kk += 64) {
        for (int p = 0; p < 4; p++) {
            int row = rowA0 + p * 32;
            *(half8_t*)(&lA[row][col8]) =
                *(const half8_t*)(aT + ((size_t)(b * 1024) + t0 + row) * 512 + kk + col8);
            *(half8_t*)(&lB[row][col8]) =
                *(const half8_t*)(pw16 + (size_t)(o0 + row) * 512 + kk + col8);
        }
        __syncthreads();
        for (int ks = 0; ks < 2; ks++) {
            int colk = ks * 32 + l4 * 8;
            half8_t a[4], bb[4];
            for (int mi = 0; mi < 4; mi++) a[mi]  = *(const half8_t*)(&lA[wr * 64 + mi * 16 + l15][colk]);
            for (int ni = 0; ni < 4; ni++) bb[ni] = *(const half8_t*)(&lB[wc * 64 + ni * 16 + l15][colk]);
            for (int mi = 0; mi < 4; mi++)
                for (int ni = 0; ni < 4; ni++)
                    acc[mi][ni] = __builtin_amdgcn_mfma_f32_16x16x32_f16(a[mi], bb[ni], acc[mi][ni], 0, 0, 0);
        }
        __syncthreads();
    }
    for (int ni = 0; ni < 4; ni++) {
        int o = o0 + wc * 64 + ni * 16 + l15;
        float bias = proj_b[o];
        for (int mi = 0; mi < 4; mi++) {
            int t = t0 + wr * 64 + mi * 16 + l4 * 4;
            size_t idx = ((size_t)(b * 512) + o) * 1024 + t;
            float4_t xres = *(const float4_t*)(x + idx);
            float4_t ov;
            for (int j = 0; j < 4; j++) ov[j] = acc[mi][ni][j] + bias + xres[j];
            *(float4_t*)(out + idx) = ov;
        }
    }
}

extern "C" void kernel_launch(void* const* d_in, const int* in_sizes, int n_in,
                              void* d_out, int out_size, void* d_ws, size_t ws_size,
                              hipStream_t stream) {
    const float* x        = (const float*)d_in[0];
    const float* gn_scale = (const float*)d_in[1];
    const float* gn_bias  = (const float*)d_in[2];
    const float* qkv_w    = (const float*)d_in[3];
    const float* qkv_b    = (const float*)d_in[4];
    const float* proj_w   = (const float*)d_in[5];
    const float* proj_b   = (const float*)d_in[6];
    float* out = (float*)d_out;

    char* ws = (char*)d_ws;
    half_t* w16  = (half_t*)(ws + OFF_W16);
    half_t* pw16 = (half_t*)(ws + OFF_PW16);
    half_t* xnT  = (half_t*)(ws + OFF_XNT);
    half_t* qkv  = (half_t*)(ws + OFF_QKV);
    half_t* aT   = (half_t*)(ws + OFF_AT);
    float*  stat = (float*) (ws + OFF_STAT);

    k_convert_w<<<1024, 256, 0, stream>>>(qkv_w, proj_w, w16, pw16);
    k_gn_stats<<<512, 256, 0, stream>>>(x, stat);
    k_gn_apply_t<<<2048, 256, 0, stream>>>(x, stat, gn_scale, gn_bias, xnT);
    k_qkv_gemm<<<1536, 256, 0, stream>>>(xnT, w16, qkv_b, qkv);
    k_attn<<<2048, 256, 0, stream>>>(qkv, aT);
    k_proj_gemm<<<512, 256, 0, stream>>>(aT, pw16, proj_b, x, out);
}

// Round 2
// 273.215 us; speedup vs baseline: 1.1349x; 1.1349x over previous
//
#include <hip/hip_runtime.h>

typedef _Float16 half_t;
typedef _Float16 half4_t __attribute__((ext_vector_type(4)));
typedef _Float16 half8_t __attribute__((ext_vector_type(8)));
typedef float f32x4 __attribute__((ext_vector_type(4)));
typedef float float4_t __attribute__((ext_vector_type(4)));

#define NB 16
#define NC 512
#define NT 1024
#define NHEAD 8
#define DH 64

// ---------------- workspace layout (bytes) ----------------
#define OFF_W16  ((size_t)0)                                  // qkv_w fp16 [1536][512]
#define OFF_PW16 (OFF_W16  + (size_t)1536*512*2)              // proj_w fp16 [512][512]
#define OFF_XNT  (OFF_PW16 + (size_t)512*512*2)               // xnT fp16 [16][1024][512]
#define OFF_QKV  (OFF_XNT  + (size_t)16*1024*512*2)           // qkv fp16 [16][1536][1024]
#define OFF_AT   (OFF_QKV  + (size_t)16*1536*1024*2)          // aT  fp16 [16][1024][512]
#define OFF_STAT (OFF_AT   + (size_t)16*1024*512*2)           // stats f32 [16][32][2]

// ---------------- K0: weights fp32 -> fp16 ----------------
__global__ void k_convert_w(const float* __restrict__ qkv_w, const float* __restrict__ proj_w,
                            half_t* __restrict__ w16, half_t* __restrict__ pw16) {
    int i = (blockIdx.x * 256 + threadIdx.x) * 4;
    const int NQ = 1536 * 512;
    if (i < NQ) {
        float4_t v = *(const float4_t*)(qkv_w + i);
        half4_t h; for (int j = 0; j < 4; j++) h[j] = (half_t)v[j];
        *(half4_t*)(w16 + i) = h;
    } else {
        int k = i - NQ;
        float4_t v = *(const float4_t*)(proj_w + k);
        half4_t h; for (int j = 0; j < 4; j++) h[j] = (half_t)v[j];
        *(half4_t*)(pw16 + k) = h;
    }
}

// ---------------- K1: per-(b,group) mean / rsigma ----------------
__global__ void k_gn_stats(const float* __restrict__ x, float* __restrict__ stats) {
    int bg = blockIdx.x;                       // b*32+g ; group = 16 ch * 1024 = 16384 contiguous floats
    const float* p = x + (size_t)bg * 16384;
    float s = 0.f, sq = 0.f;
    for (int i = threadIdx.x; i < 4096; i += 256) {
        float4_t v = *(const float4_t*)(p + i * 4);
        for (int j = 0; j < 4; j++) { s += v[j]; sq += v[j] * v[j]; }
    }
    for (int m = 1; m < 64; m <<= 1) { s += __shfl_xor(s, m, 64); sq += __shfl_xor(sq, m, 64); }
    __shared__ float red[2][4];
    int wid = threadIdx.x >> 6;
    if ((threadIdx.x & 63) == 0) { red[0][wid] = s; red[1][wid] = sq; }
    __syncthreads();
    if (threadIdx.x == 0) {
        s  = red[0][0] + red[0][1] + red[0][2] + red[0][3];
        sq = red[1][0] + red[1][1] + red[1][2] + red[1][3];
        float mean = s * (1.f / 16384.f);
        float var  = sq * (1.f / 16384.f) - mean * mean;
        stats[bg * 2]     = mean;
        stats[bg * 2 + 1] = rsqrtf(var + 1e-5f);
    }
}

// ---------------- K2: normalize + scale/bias + fp16 + transpose -> xnT[b][t][c] ----------------
__global__ void k_gn_apply_t(const float* __restrict__ x, const float* __restrict__ stats,
                             const float* __restrict__ scale, const float* __restrict__ bias,
                             half_t* __restrict__ xnT) {
    int bx = blockIdx.x;            // 16 * 8 * 16
    int b = bx >> 7;
    int r = bx & 127;
    int c0 = (r >> 4) * 64;
    int t0 = (r & 15) * 64;
    __shared__ half_t lds[64][72];
    int ci = threadIdx.x >> 4;          // 0..15
    int tj = (threadIdx.x & 15) * 4;
    for (int p = 0; p < 4; p++) {
        int c = c0 + ci + p * 16;
        float mean = stats[(b * 32 + (c >> 4)) * 2];
        float rsig = stats[(b * 32 + (c >> 4)) * 2 + 1];
        float sc = scale[c] * rsig;
        float bs = bias[c] - mean * sc;
        float4_t v = *(const float4_t*)(x + ((size_t)(b * 512 + c)) * 1024 + t0 + tj);
        half4_t hx;
        for (int j = 0; j < 4; j++) hx[j] = (half_t)(v[j] * sc + bs);
        *(half4_t*)(&lds[ci + p * 16][tj]) = hx;
    }
    __syncthreads();
    int cj = (threadIdx.x & 7) * 8;
    int ti = threadIdx.x >> 3;          // 0..31
    for (int p = 0; p < 2; p++) {
        int t = ti + p * 32;
        half8_t h;
        for (int j = 0; j < 8; j++) h[j] = lds[cj + j][t];
        *(half8_t*)(xnT + ((size_t)(b * 1024 + t0 + t)) * 512 + c0 + cj) = h;
    }
}

// ---------------- K3: QKV GEMM  (M=t 128, N=o 128, K=c 512) ----------------
__global__ __launch_bounds__(256) void k_qkv_gemm(const half_t* __restrict__ xnT,
                                                  const half_t* __restrict__ w16,
                                                  const float* __restrict__ qkv_b,
                                                  half_t* __restrict__ qkv) {
    int bx = blockIdx.x;            // 16 * 8 * 12
    int b = bx / 96;
    int r = bx % 96;
    int t0 = (r / 12) * 128;
    int o0 = (r % 12) * 128;
    __shared__ half_t lA[128][72];
    __shared__ half_t lB[128][72];
    int tid = threadIdx.x;
    int lane = tid & 63, wid = tid >> 6;
    int wr = wid >> 1, wc = wid & 1;
    int l15 = lane & 15, l4 = lane >> 4;
    f32x4 acc[4][4] = {};
    const int rowA0 = tid >> 3;          // 0..31
    const int col8 = (tid & 7) * 8;
    for (int kk = 0; kk < 512; kk += 64) {
        for (int p = 0; p < 4; p++) {
            int row = rowA0 + p * 32;
            *(half8_t*)(&lA[row][col8]) =
                *(const half8_t*)(xnT + ((size_t)(b * 1024) + t0 + row) * 512 + kk + col8);
            *(half8_t*)(&lB[row][col8]) =
                *(const half8_t*)(w16 + (size_t)(o0 + row) * 512 + kk + col8);
        }
        __syncthreads();
        for (int ks = 0; ks < 2; ks++) {
            int colk = ks * 32 + l4 * 8;
            half8_t a[4], bb[4];
            for (int mi = 0; mi < 4; mi++) a[mi]  = *(const half8_t*)(&lA[wr * 64 + mi * 16 + l15][colk]);
            for (int ni = 0; ni < 4; ni++) bb[ni] = *(const half8_t*)(&lB[wc * 64 + ni * 16 + l15][colk]);
            for (int mi = 0; mi < 4; mi++)
                for (int ni = 0; ni < 4; ni++)
                    acc[mi][ni] = __builtin_amdgcn_mfma_f32_16x16x32_f16(a[mi], bb[ni], acc[mi][ni], 0, 0, 0);
        }
        __syncthreads();
    }
    for (int ni = 0; ni < 4; ni++) {
        int o = o0 + wc * 64 + ni * 16 + l15;
        float bias = qkv_b[o];
        for (int mi = 0; mi < 4; mi++) {
            int t = t0 + wr * 64 + mi * 16 + l4 * 4;
            half4_t h;
            for (int j = 0; j < 4; j++) h[j] = (half_t)(acc[mi][ni][j] + bias);
            *(half4_t*)(qkv + ((size_t)(b * 1536) + o) * 1024 + t) = h;
        }
    }
}

// ---------------- K4: flash attention per (b,h,t-tile of 64) ----------------
// Swapped-operand QK^T: S^T = K^T · Q  =>  lane owns one q-column (col = lane&15),
// 16 lane-local s-values => softmax needs only 2 shfl_xor; f and 1/l are lane-local.
__global__ __launch_bounds__(256) void k_attn(const half_t* __restrict__ qkv, half_t* __restrict__ aT) {
    int bx = blockIdx.x;            // 128 * 16
    int bh = bx >> 4;
    int t0 = (bx & 15) * 64;
    int b = bh >> 3, h = bh & 7;
    const half_t* qb = qkv + ((size_t)(b * 1536) + h * 64) * 1024;
    const half_t* kb = qb + (size_t)512 * 1024;
    const half_t* vb = qb + (size_t)1024 * 1024;

    __shared__ half_t smq[64][72];     // q^T staging, then reused as P[t][s] (per-wave rows)
    __shared__ half_t lkT[64][72];     // [s][d]
    __shared__ half_t lv [64][72];     // [d][s]

    int tid = threadIdx.x;
    int lane = tid & 63, w = tid >> 6;
    int l15 = lane & 15, l4 = lane >> 4;

    // stage q transposed (wave w writes+reads only its own rows w*16..w*16+15)
    {
        int d = lane;
        for (int hf = 0; hf < 2; hf++) {
            half8_t v = *(const half8_t*)(qb + (size_t)d * 1024 + t0 + w * 16 + hf * 8);
            for (int j = 0; j < 8; j++) smq[w * 16 + hf * 8 + j][d] = v[j];
        }
    }
    half8_t bq[2];   // B-frag: B[k=d][col=q]; same-wave LDS dep only
    for (int ks = 0; ks < 2; ks++)
        bq[ks] = *(const half8_t*)(&smq[w * 16 + l15][ks * 32 + l4 * 8]);

    f32x4 oacc[4] = {};
    float m_ = -1e30f, l_ = 0.f;
    const float SC = 0.18033688f;      // 0.125 * log2(e) -> exp2 domain

    for (int it = 0; it < 16; it++) {
        int s0 = it * 64;
        __syncthreads();   // protect lkT/lv from previous iteration's readers
        {
            int d = lane;
            for (int hf = 0; hf < 2; hf++) {
                half8_t kv = *(const half8_t*)(kb + (size_t)d * 1024 + s0 + w * 16 + hf * 8);
                for (int j = 0; j < 8; j++) lkT[w * 16 + hf * 8 + j][d] = kv[j];
                half8_t vv = *(const half8_t*)(vb + (size_t)d * 1024 + s0 + w * 16 + hf * 8);
                *(half8_t*)(&lv[d][w * 16 + hf * 8]) = vv;
            }
        }
        __syncthreads();
        // S^T tile: st[ni][r] = S[s0+ni*16+l4*4+r][t0+w*16+l15] (scaled)
        f32x4 st[4] = {};
        for (int ks = 0; ks < 2; ks++) {
            int colk = ks * 32 + l4 * 8;
            for (int ni = 0; ni < 4; ni++) {
                half8_t ak = *(const half8_t*)(&lkT[ni * 16 + l15][colk]);
                st[ni] = __builtin_amdgcn_mfma_f32_16x16x32_f16(ak, bq[ks], st[ni], 0, 0, 0);
            }
        }
        for (int ni = 0; ni < 4; ni++)
            for (int r = 0; r < 4; r++) st[ni][r] *= SC;
        // lane-local tile max (16 vals) + 2-step cross-group reduce
        float tm = st[0][0];
        for (int ni = 0; ni < 4; ni++)
            for (int r = 0; r < 4; r++) tm = fmaxf(tm, st[ni][r]);
        tm = fmaxf(tm, __shfl_xor(tm, 16, 64));
        tm = fmaxf(tm, __shfl_xor(tm, 32, 64));
        float nm = fmaxf(m_, tm);
        float f = exp2f(m_ - nm);
        float ps = 0.f;
        for (int ni = 0; ni < 4; ni++) {
            half4_t ph;
            for (int r = 0; r < 4; r++) {
                float p = exp2f(st[ni][r] - nm);
                ps += p;
                ph[r] = (half_t)p;
            }
            *(half4_t*)(&smq[w * 16 + l15][ni * 16 + l4 * 4]) = ph;   // P[t][s], half4
        }
        ps += __shfl_xor(ps, 16, 64);
        ps += __shfl_xor(ps, 32, 64);
        l_ = l_ * f + ps;
        m_ = nm;
        for (int mi = 0; mi < 4; mi++)
            for (int i = 0; i < 4; i++) oacc[mi][i] *= f;
        // O += V P^T : A = lv[d][s], B[k=s][col=t] = P[t][s] read row-wise
        for (int ks = 0; ks < 2; ks++) {
            int colk = ks * 32 + l4 * 8;
            half8_t bp = *(const half8_t*)(&smq[w * 16 + l15][colk]);
            for (int mi = 0; mi < 4; mi++) {
                half8_t av = *(const half8_t*)(&lv[mi * 16 + l15][colk]);
                oacc[mi] = __builtin_amdgcn_mfma_f32_16x16x32_f16(av, bp, oacc[mi], 0, 0, 0);
            }
        }
    }
    // O /= l ; store aT[b][t][h*64+d]  (col t = l15 is lane-local, rows d = mi*16+l4*4+i)
    float linv = 1.0f / l_;
    int t = t0 + w * 16 + l15;
    for (int mi = 0; mi < 4; mi++) {
        half4_t hv;
        for (int i = 0; i < 4; i++) hv[i] = (half_t)(oacc[mi][i] * linv);
        *(half4_t*)(aT + ((size_t)(b * 1024) + t) * 512 + h * 64 + mi * 16 + l4 * 4) = hv;
    }
}

// ---------------- K5: proj GEMM + bias + residual  (M=t, N=o, K=c) ----------------
__global__ __launch_bounds__(256) void k_proj_gemm(const half_t* __restrict__ aT,
                                                   const half_t* __restrict__ pw16,
                                                   const float* __restrict__ proj_b,
                                                   const float* __restrict__ x,
                                                   float* __restrict__ out) {
    int bx = blockIdx.x;            // 16 * 8 * 4
    int b = bx / 32;
    int r = bx % 32;
    int t0 = (r / 4) * 128;
    int o0 = (r % 4) * 128;
    __shared__ half_t lA[128][72];
    __shared__ half_t lB[128][72];
    int tid = threadIdx.x;
    int lane = tid & 63, wid = tid >> 6;
    int wr = wid >> 1, wc = wid & 1;
    int l15 = lane & 15, l4 = lane >> 4;
    f32x4 acc[4][4] = {};
    const int rowA0 = tid >> 3;
    const int col8 = (tid & 7) * 8;
    for (int kk = 0; kk < 512; kk += 64) {
        for (int p = 0; p < 4; p++) {
            int row = rowA0 + p * 32;
            *(half8_t*)(&lA[row][col8]) =
                *(const half8_t*)(aT + ((size_t)(b * 1024) + t0 + row) * 512 + kk + col8);
            *(half8_t*)(&lB[row][col8]) =
                *(const half8_t*)(pw16 + (size_t)(o0 + row) * 512 + kk + col8);
        }
        __syncthreads();
        for (int ks = 0; ks < 2; ks++) {
            int colk = ks * 32 + l4 * 8;
            half8_t a[4], bb[4];
            for (int mi = 0; mi < 4; mi++) a[mi]  = *(const half8_t*)(&lA[wr * 64 + mi * 16 + l15][colk]);
            for (int ni = 0; ni < 4; ni++) bb[ni] = *(const half8_t*)(&lB[wc * 64 + ni * 16 + l15][colk]);
            for (int mi = 0; mi < 4; mi++)
                for (int ni = 0; ni < 4; ni++)
                    acc[mi][ni] = __builtin_amdgcn_mfma_f32_16x16x32_f16(a[mi], bb[ni], acc[mi][ni], 0, 0, 0);
        }
        __syncthreads();
    }
    for (int ni = 0; ni < 4; ni++) {
        int o = o0 + wc * 64 + ni * 16 + l15;
        float bias = proj_b[o];
        for (int mi = 0; mi < 4; mi++) {
            int t = t0 + wr * 64 + mi * 16 + l4 * 4;
            size_t idx = ((size_t)(b * 512) + o) * 1024 + t;
            float4_t xres = *(const float4_t*)(x + idx);
            float4_t ov;
            for (int j = 0; j < 4; j++) ov[j] = acc[mi][ni][j] + bias + xres[j];
            *(float4_t*)(out + idx) = ov;
        }
    }
}

extern "C" void kernel_launch(void* const* d_in, const int* in_sizes, int n_in,
                              void* d_out, int out_size, void* d_ws, size_t ws_size,
                              hipStream_t stream) {
    const float* x        = (const float*)d_in[0];
    const float* gn_scale = (const float*)d_in[1];
    const float* gn_bias  = (const float*)d_in[2];
    const float* qkv_w    = (const float*)d_in[3];
    const float* qkv_b    = (const float*)d_in[4];
    const float* proj_w   = (const float*)d_in[5];
    const float* proj_b   = (const float*)d_in[6];
    float* out = (float*)d_out;

    char* ws = (char*)d_ws;
    half_t* w16  = (half_t*)(ws + OFF_W16);
    half_t* pw16 = (half_t*)(ws + OFF_PW16);
    half_t* xnT  = (half_t*)(ws + OFF_XNT);
    half_t* qkv  = (half_t*)(ws + OFF_QKV);
    half_t* aT   = (half_t*)(ws + OFF_AT);
    float*  stat = (float*) (ws + OFF_STAT);

    k_convert_w<<<1024, 256, 0, stream>>>(qkv_w, proj_w, w16, pw16);
    k_gn_stats<<<512, 256, 0, stream>>>(x, stat);
    k_gn_apply_t<<<2048, 256, 0, stream>>>(x, stat, gn_scale, gn_bias, xnT);
    k_qkv_gemm<<<1536, 256, 0, stream>>>(xnT, w16, qkv_b, qkv);
    k_attn<<<2048, 256, 0, stream>>>(qkv, aT);
    k_proj_gemm<<<512, 256, 0, stream>>>(aT, pw16, proj_b, x, out);
}

// Round 3
// 267.054 us; speedup vs baseline: 1.1611x; 1.0231x over previous
//
#include <hip/hip_runtime.h>

typedef _Float16 half_t;
typedef _Float16 half4_t __attribute__((ext_vector_type(4)));
typedef _Float16 half8_t __attribute__((ext_vector_type(8)));
typedef float f32x4 __attribute__((ext_vector_type(4)));
typedef float float4_t __attribute__((ext_vector_type(4)));

#define NB 16
#define NC 512
#define NT 1024
#define NHEAD 8
#define DH 64

// ---------------- workspace layout (bytes) ----------------
#define OFF_W16  ((size_t)0)                                  // qkv_w fp16 [1536][512]
#define OFF_PW16 (OFF_W16  + (size_t)1536*512*2)              // proj_w fp16 [512][512]
#define OFF_XNT  (OFF_PW16 + (size_t)512*512*2)               // xnT fp16 [16][1024][512]
#define OFF_QKV  (OFF_XNT  + (size_t)16*1024*512*2)           // qkv fp16 [16][1536][1024]
#define OFF_AT   (OFF_QKV  + (size_t)16*1536*1024*2)          // aT  fp16 [16][1024][512]
#define OFF_STAT (OFF_AT   + (size_t)16*1024*512*2)           // stats f32 [16][32][2]

// async global->LDS, 16B per lane; LDS dest = base + lane*16 (wave-uniform base)
__device__ __forceinline__ void gload16(const half_t* g, half_t* l) {
    __builtin_amdgcn_global_load_lds(
        (const __attribute__((address_space(1))) void*)g,
        (__attribute__((address_space(3))) void*)l, 16, 0, 0);
}

// XOR-swizzled LDS address for 64x64 half tiles (row stride 128B):
// byte = (row*128 + col*2) ^ ((row&7)<<4)  -- keeps 16B groups intact, spreads
// the 16-lane same-column read across 8 bank groups (2-way = free).
__device__ __forceinline__ half_t* swz(half_t* base, int row, int col) {
    int byte = ((row << 7) + (col << 1)) ^ ((row & 7) << 4);
    return (half_t*)((char*)base + byte);
}

// ---------------- K0: weights fp32 -> fp16 ----------------
__global__ void k_convert_w(const float* __restrict__ qkv_w, const float* __restrict__ proj_w,
                            half_t* __restrict__ w16, half_t* __restrict__ pw16) {
    int i = (blockIdx.x * 256 + threadIdx.x) * 4;
    const int NQ = 1536 * 512;
    if (i < NQ) {
        float4_t v = *(const float4_t*)(qkv_w + i);
        half4_t h; for (int j = 0; j < 4; j++) h[j] = (half_t)v[j];
        *(half4_t*)(w16 + i) = h;
    } else {
        int k = i - NQ;
        float4_t v = *(const float4_t*)(proj_w + k);
        half4_t h; for (int j = 0; j < 4; j++) h[j] = (half_t)v[j];
        *(half4_t*)(pw16 + k) = h;
    }
}

// ---------------- K1: per-(b,group) mean / rsigma ----------------
__global__ void k_gn_stats(const float* __restrict__ x, float* __restrict__ stats) {
    int bg = blockIdx.x;                       // b*32+g ; group = 16 ch * 1024 = 16384 contiguous floats
    const float* p = x + (size_t)bg * 16384;
    float s = 0.f, sq = 0.f;
    for (int i = threadIdx.x; i < 4096; i += 256) {
        float4_t v = *(const float4_t*)(p + i * 4);
        for (int j = 0; j < 4; j++) { s += v[j]; sq += v[j] * v[j]; }
    }
    for (int m = 1; m < 64; m <<= 1) { s += __shfl_xor(s, m, 64); sq += __shfl_xor(sq, m, 64); }
    __shared__ float red[2][4];
    int wid = threadIdx.x >> 6;
    if ((threadIdx.x & 63) == 0) { red[0][wid] = s; red[1][wid] = sq; }
    __syncthreads();
    if (threadIdx.x == 0) {
        s  = red[0][0] + red[0][1] + red[0][2] + red[0][3];
        sq = red[1][0] + red[1][1] + red[1][2] + red[1][3];
        float mean = s * (1.f / 16384.f);
        float var  = sq * (1.f / 16384.f) - mean * mean;
        stats[bg * 2]     = mean;
        stats[bg * 2 + 1] = rsqrtf(var + 1e-5f);
    }
}

// ---------------- K2: normalize + scale/bias + fp16 + transpose -> xnT[b][t][c] ----------------
__global__ void k_gn_apply_t(const float* __restrict__ x, const float* __restrict__ stats,
                             const float* __restrict__ scale, const float* __restrict__ bias,
                             half_t* __restrict__ xnT) {
    int bx = blockIdx.x;            // 16 * 8 * 16
    int b = bx >> 7;
    int r = bx & 127;
    int c0 = (r >> 4) * 64;
    int t0 = (r & 15) * 64;
    __shared__ half_t lds[64][72];
    int ci = threadIdx.x >> 4;          // 0..15
    int tj = (threadIdx.x & 15) * 4;
    for (int p = 0; p < 4; p++) {
        int c = c0 + ci + p * 16;
        float mean = stats[(b * 32 + (c >> 4)) * 2];
        float rsig = stats[(b * 32 + (c >> 4)) * 2 + 1];
        float sc = scale[c] * rsig;
        float bs = bias[c] - mean * sc;
        float4_t v = *(const float4_t*)(x + ((size_t)(b * 512 + c)) * 1024 + t0 + tj);
        half4_t hx;
        for (int j = 0; j < 4; j++) hx[j] = (half_t)(v[j] * sc + bs);
        *(half4_t*)(&lds[ci + p * 16][tj]) = hx;
    }
    __syncthreads();
    int cj = (threadIdx.x & 7) * 8;
    int ti = threadIdx.x >> 3;          // 0..31
    for (int p = 0; p < 2; p++) {
        int t = ti + p * 32;
        half8_t h;
        for (int j = 0; j < 8; j++) h[j] = lds[cj + j][t];
        *(half8_t*)(xnT + ((size_t)(b * 1024 + t0 + t)) * 512 + c0 + cj) = h;
    }
}

// ---------------- K3: QKV GEMM  (M=t 128, N=o 128, K=c 512), global_load_lds staging ----------------
__global__ __launch_bounds__(256) void k_qkv_gemm(const half_t* __restrict__ xnT,
                                                  const half_t* __restrict__ w16,
                                                  const float* __restrict__ qkv_b,
                                                  half_t* __restrict__ qkv) {
    int bx = blockIdx.x;            // 16 * 8 * 12
    int b = bx / 96;
    int r = bx % 96;
    int t0 = (r / 12) * 128;
    int o0 = (r % 12) * 128;
    __shared__ half_t lA[128 * 64];   // linear, row stride 64 halfwords (gload_lds needs linear dest)
    __shared__ half_t lB[128 * 64];
    int tid = threadIdx.x;
    int lane = tid & 63, w = tid >> 6;
    int wr = w >> 1, wc = w & 1;
    int l15 = lane & 15, l4 = lane >> 4;
    int srow = lane >> 3, scol = (lane & 7) * 8;    // lane's slot inside an 8-row stripe
    const half_t* gA = xnT + ((size_t)(b * 1024) + t0) * 512;
    const half_t* gB = w16 + (size_t)o0 * 512;
    f32x4 acc[4][4] = {};
    for (int kk = 0; kk < 512; kk += 64) {
        for (int p = 0; p < 4; p++) {          // wave w stages rows w*32 .. w*32+31 of A and B
            int row = w * 32 + p * 8;
            gload16(gA + (size_t)(row + srow) * 512 + kk + scol, &lA[row * 64]);
            gload16(gB + (size_t)(row + srow) * 512 + kk + scol, &lB[row * 64]);
        }
        __syncthreads();
        for (int ks = 0; ks < 2; ks++) {
            int colk = ks * 32 + l4 * 8;
            half8_t a[4], bb[4];
            for (int mi = 0; mi < 4; mi++) a[mi]  = *(const half8_t*)(&lA[(wr * 64 + mi * 16 + l15) * 64 + colk]);
            for (int ni = 0; ni < 4; ni++) bb[ni] = *(const half8_t*)(&lB[(wc * 64 + ni * 16 + l15) * 64 + colk]);
            for (int mi = 0; mi < 4; mi++)
                for (int ni = 0; ni < 4; ni++)
                    acc[mi][ni] = __builtin_amdgcn_mfma_f32_16x16x32_f16(a[mi], bb[ni], acc[mi][ni], 0, 0, 0);
        }
        __syncthreads();
    }
    for (int ni = 0; ni < 4; ni++) {
        int o = o0 + wc * 64 + ni * 16 + l15;
        float bias = qkv_b[o];
        for (int mi = 0; mi < 4; mi++) {
            int t = t0 + wr * 64 + mi * 16 + l4 * 4;
            half4_t h;
            for (int j = 0; j < 4; j++) h[j] = (half_t)(acc[mi][ni][j] + bias);
            *(half4_t*)(qkv + ((size_t)(b * 1536) + o) * 1024 + t) = h;
        }
    }
}

// ---------------- K4: flash attention per (b,h,t-tile of 64) ----------------
// Swapped-operand QK^T (lane owns one q-column), exp2-domain softmax with the
// full scale folded into staged q, defer-max rescale (THR=8 in log2 domain),
// XOR-swizzled unpadded LDS tiles (conflict-free frag reads).
__global__ __launch_bounds__(256) void k_attn(const half_t* __restrict__ qkv, half_t* __restrict__ aT) {
    int bx = blockIdx.x;            // 128 * 16
    int bh = bx >> 4;
    int t0 = (bx & 15) * 64;
    int b = bh >> 3, h = bh & 7;
    const half_t* qb = qkv + ((size_t)(b * 1536) + h * 64) * 1024;
    const half_t* kb = qb + (size_t)512 * 1024;
    const half_t* vb = qb + (size_t)1024 * 1024;

    __shared__ half_t smq[64 * 64];    // q^T staging (pre-scaled), then P[t][s] per-wave rows
    __shared__ half_t lkT[64 * 64];    // [s][d]
    __shared__ half_t lv [64 * 64];    // [d][s]

    int tid = threadIdx.x;
    int lane = tid & 63, w = tid >> 6;
    int l15 = lane & 15, l4 = lane >> 4;
    const float SC = 0.18033688f;      // 0.125 * log2(e): QK^T comes out in exp2 domain

    // stage q transposed, pre-scaled (wave w touches only its rows w*16..w*16+15)
    {
        int d = lane;
        for (int hf = 0; hf < 2; hf++) {
            half8_t v = *(const half8_t*)(qb + (size_t)d * 1024 + t0 + w * 16 + hf * 8);
            for (int j = 0; j < 8; j++)
                *swz(smq, w * 16 + hf * 8 + j, d) = (half_t)((float)v[j] * SC);
        }
    }
    half8_t bq[2];   // B-frag: B[k=d][col=q]; same-wave LDS dep only
    for (int ks = 0; ks < 2; ks++)
        bq[ks] = *(const half8_t*)swz(smq, w * 16 + l15, ks * 32 + l4 * 8);

    f32x4 oacc[4] = {};
    float m_ = -1e30f, l_ = 0.f;

    for (int it = 0; it < 16; it++) {
        int s0 = it * 64;
        __syncthreads();   // protect lkT/lv from previous iteration's readers
        {
            int d = lane;
            for (int hf = 0; hf < 2; hf++) {
                half8_t kv = *(const half8_t*)(kb + (size_t)d * 1024 + s0 + w * 16 + hf * 8);
                for (int j = 0; j < 8; j++) *swz(lkT, w * 16 + hf * 8 + j, d) = kv[j];
                half8_t vv = *(const half8_t*)(vb + (size_t)d * 1024 + s0 + w * 16 + hf * 8);
                *(half8_t*)swz(lv, d, w * 16 + hf * 8) = vv;
            }
        }
        __syncthreads();
        // S^T tile (exp2 domain): st[ni][r] = S2[s0+ni*16+l4*4+r][t0+w*16+l15]
        f32x4 st[4] = {};
        for (int ks = 0; ks < 2; ks++) {
            int colk = ks * 32 + l4 * 8;
            for (int ni = 0; ni < 4; ni++) {
                half8_t ak = *(const half8_t*)swz(lkT, ni * 16 + l15, colk);
                st[ni] = __builtin_amdgcn_mfma_f32_16x16x32_f16(ak, bq[ks], st[ni], 0, 0, 0);
            }
        }
        // lane-local tile max (16 vals) + 2-step cross-group reduce
        float tm = st[0][0];
        for (int ni = 0; ni < 4; ni++)
            for (int r = 0; r < 4; r++) tm = fmaxf(tm, st[ni][r]);
        tm = fmaxf(tm, __shfl_xor(tm, 16, 64));
        tm = fmaxf(tm, __shfl_xor(tm, 32, 64));
        // defer-max: rescale O only when the running max grew by > 8 (P bounded by 2^8)
        if (__any(tm > m_ + 8.0f)) {
            float nm = fmaxf(m_, tm);
            float f = exp2f(m_ - nm);
            l_ *= f;
            for (int mi = 0; mi < 4; mi++)
                for (int i = 0; i < 4; i++) oacc[mi][i] *= f;
            m_ = nm;
        }
        float ps = 0.f;
        for (int ni = 0; ni < 4; ni++) {
            half4_t ph;
            for (int r = 0; r < 4; r++) {
                float p = exp2f(st[ni][r] - m_);
                ps += p;
                ph[r] = (half_t)p;
            }
            *(half4_t*)swz(smq, w * 16 + l15, ni * 16 + l4 * 4) = ph;   // P[t][s]
        }
        ps += __shfl_xor(ps, 16, 64);
        ps += __shfl_xor(ps, 32, 64);
        l_ += ps;
        // O += V P^T : A = lv[d][s], B[k=s][col=t] = P[t][s] read row-wise
        for (int ks = 0; ks < 2; ks++) {
            int colk = ks * 32 + l4 * 8;
            half8_t bp = *(const half8_t*)swz(smq, w * 16 + l15, colk);
            for (int mi = 0; mi < 4; mi++) {
                half8_t av = *(const half8_t*)swz(lv, mi * 16 + l15, colk);
                oacc[mi] = __builtin_amdgcn_mfma_f32_16x16x32_f16(av, bp, oacc[mi], 0, 0, 0);
            }
        }
    }
    // O /= l ; store aT[b][t][h*64+d]  (col t = l15 lane-local, rows d = mi*16+l4*4+i)
    float linv = 1.0f / l_;
    int t = t0 + w * 16 + l15;
    for (int mi = 0; mi < 4; mi++) {
        half4_t hv;
        for (int i = 0; i < 4; i++) hv[i] = (half_t)(oacc[mi][i] * linv);
        *(half4_t*)(aT + ((size_t)(b * 1024) + t) * 512 + h * 64 + mi * 16 + l4 * 4) = hv;
    }
}

// ---------------- K5: proj GEMM + bias + residual  (M=t, N=o, K=c), global_load_lds staging ----------------
__global__ __launch_bounds__(256) void k_proj_gemm(const half_t* __restrict__ aT,
                                                   const half_t* __restrict__ pw16,
                                                   const float* __restrict__ proj_b,
                                                   const float* __restrict__ x,
                                                   float* __restrict__ out) {
    int bx = blockIdx.x;            // 16 * 8 * 4
    int b = bx / 32;
    int r = bx % 32;
    int t0 = (r / 4) * 128;
    int o0 = (r % 4) * 128;
    __shared__ half_t lA[128 * 64];
    __shared__ half_t lB[128 * 64];
    int tid = threadIdx.x;
    int lane = tid & 63, w = tid >> 6;
    int wr = w >> 1, wc = w & 1;
    int l15 = lane & 15, l4 = lane >> 4;
    int srow = lane >> 3, scol = (lane & 7) * 8;
    const half_t* gA = aT + ((size_t)(b * 1024) + t0) * 512;
    const half_t* gB = pw16 + (size_t)o0 * 512;
    f32x4 acc[4][4] = {};
    for (int kk = 0; kk < 512; kk += 64) {
        for (int p = 0; p < 4; p++) {
            int row = w * 32 + p * 8;
            gload16(gA + (size_t)(row + srow) * 512 + kk + scol, &lA[row * 64]);
            gload16(gB + (size_t)(row + srow) * 512 + kk + scol, &lB[row * 64]);
        }
        __syncthreads();
        for (int ks = 0; ks < 2; ks++) {
            int colk = ks * 32 + l4 * 8;
            half8_t a[4], bb[4];
            for (int mi = 0; mi < 4; mi++) a[mi]  = *(const half8_t*)(&lA[(wr * 64 + mi * 16 + l15) * 64 + colk]);
            for (int ni = 0; ni < 4; ni++) bb[ni] = *(const half8_t*)(&lB[(wc * 64 + ni * 16 + l15) * 64 + colk]);
            for (int mi = 0; mi < 4; mi++)
                for (int ni = 0; ni < 4; ni++)
                    acc[mi][ni] = __builtin_amdgcn_mfma_f32_16x16x32_f16(a[mi], bb[ni], acc[mi][ni], 0, 0, 0);
        }
        __syncthreads();
    }
    for (int ni = 0; ni < 4; ni++) {
        int o = o0 + wc * 64 + ni * 16 + l15;
        float bias = proj_b[o];
        for (int mi = 0; mi < 4; mi++) {
            int t = t0 + wr * 64 + mi * 16 + l4 * 4;
            size_t idx = ((size_t)(b * 512) + o) * 1024 + t;
            float4_t xres = *(const float4_t*)(x + idx);
            float4_t ov;
            for (int j = 0; j < 4; j++) ov[j] = acc[mi][ni][j] + bias + xres[j];
            *(float4_t*)(out + idx) = ov;
        }
    }
}

extern "C" void kernel_launch(void* const* d_in, const int* in_sizes, int n_in,
                              void* d_out, int out_size, void* d_ws, size_t ws_size,
                              hipStream_t stream) {
    const float* x        = (const float*)d_in[0];
    const float* gn_scale = (const float*)d_in[1];
    const float* gn_bias  = (const float*)d_in[2];
    const float* qkv_w    = (const float*)d_in[3];
    const float* qkv_b    = (const float*)d_in[4];
    const float* proj_w   = (const float*)d_in[5];
    const float* proj_b   = (const float*)d_in[6];
    float* out = (float*)d_out;

    char* ws = (char*)d_ws;
    half_t* w16  = (half_t*)(ws + OFF_W16);
    half_t* pw16 = (half_t*)(ws + OFF_PW16);
    half_t* xnT  = (half_t*)(ws + OFF_XNT);
    half_t* qkv  = (half_t*)(ws + OFF_QKV);
    half_t* aT   = (half_t*)(ws + OFF_AT);
    float*  stat = (float*) (ws + OFF_STAT);

    k_convert_w<<<1024, 256, 0, stream>>>(qkv_w, proj_w, w16, pw16);
    k_gn_stats<<<512, 256, 0, stream>>>(x, stat);
    k_gn_apply_t<<<2048, 256, 0, stream>>>(x, stat, gn_scale, gn_bias, xnT);
    k_qkv_gemm<<<1536, 256, 0, stream>>>(xnT, w16, qkv_b, qkv);
    k_attn<<<2048, 256, 0, stream>>>(qkv, aT);
    k_proj_gemm<<<512, 256, 0, stream>>>(aT, pw16, proj_b, x, out);
}

// Round 4
// 258.240 us; speedup vs baseline: 1.2007x; 1.0341x over previous
//
#include <hip/hip_runtime.h>

typedef _Float16 half_t;
typedef _Float16 half4_t __attribute__((ext_vector_type(4)));
typedef _Float16 half8_t __attribute__((ext_vector_type(8)));
typedef float f32x4 __attribute__((ext_vector_type(4)));
typedef float float4_t __attribute__((ext_vector_type(4)));

#define NB 16
#define NC 512
#define NT 1024
#define NHEAD 8
#define DH 64

// ---------------- workspace layout (bytes) ----------------
#define OFF_W16  ((size_t)0)                                  // qkv_w fp16 [1536][512]
#define OFF_PW16 (OFF_W16  + (size_t)1536*512*2)              // proj_w fp16 [512][512]
#define OFF_XNT  (OFF_PW16 + (size_t)512*512*2)               // xnT fp16 [16][1024][512]
#define OFF_QT   (OFF_XNT  + (size_t)16*1024*512*2)           // qT  fp16 [16][8][1024][64]
#define OFF_KT   (OFF_QT   + (size_t)16*8*1024*64*2)          // kT  fp16 [16][8][1024][64]
#define OFF_V    (OFF_KT   + (size_t)16*8*1024*64*2)          // v   fp16 [16][512][1024]
#define OFF_AT   (OFF_V    + (size_t)16*512*1024*2)           // aT  fp16 [16][1024][512]
#define OFF_STAT (OFF_AT   + (size_t)16*1024*512*2)           // stats f32 [16][32][2]

// async global->LDS, 16B per lane; LDS dest = wave-uniform base + lane*16
__device__ __forceinline__ void gload16(const half_t* g, half_t* l) {
    __builtin_amdgcn_global_load_lds(
        (const __attribute__((address_space(1))) void*)g,
        (__attribute__((address_space(3))) void*)l, 16, 0, 0);
}

// XOR-swizzled LDS address for tiles with 128B row stride:
// byte = (row*128 + col*2) ^ ((row&7)<<4); 16B-chunk-preserving, bijective.
__device__ __forceinline__ half_t* swz(half_t* base, int row, int col) {
    int byte = ((row << 7) + (col << 1)) ^ ((row & 7) << 4);
    return (half_t*)((char*)base + byte);
}

// ---------------- K0: weights fp32 -> fp16 ----------------
__global__ void k_convert_w(const float* __restrict__ qkv_w, const float* __restrict__ proj_w,
                            half_t* __restrict__ w16, half_t* __restrict__ pw16) {
    int i = (blockIdx.x * 256 + threadIdx.x) * 4;
    const int NQ = 1536 * 512;
    if (i < NQ) {
        float4_t v = *(const float4_t*)(qkv_w + i);
        half4_t h; for (int j = 0; j < 4; j++) h[j] = (half_t)v[j];
        *(half4_t*)(w16 + i) = h;
    } else {
        int k = i - NQ;
        float4_t v = *(const float4_t*)(proj_w + k);
        half4_t h; for (int j = 0; j < 4; j++) h[j] = (half_t)v[j];
        *(half4_t*)(pw16 + k) = h;
    }
}

// ---------------- K1: per-(b,group) mean / rsigma ----------------
__global__ void k_gn_stats(const float* __restrict__ x, float* __restrict__ stats) {
    int bg = blockIdx.x;                       // b*32+g ; group = 16 ch * 1024 contiguous floats
    const float* p = x + (size_t)bg * 16384;
    float s = 0.f, sq = 0.f;
    for (int i = threadIdx.x; i < 4096; i += 256) {
        float4_t v = *(const float4_t*)(p + i * 4);
        for (int j = 0; j < 4; j++) { s += v[j]; sq += v[j] * v[j]; }
    }
    for (int m = 1; m < 64; m <<= 1) { s += __shfl_xor(s, m, 64); sq += __shfl_xor(sq, m, 64); }
    __shared__ float red[2][4];
    int wid = threadIdx.x >> 6;
    if ((threadIdx.x & 63) == 0) { red[0][wid] = s; red[1][wid] = sq; }
    __syncthreads();
    if (threadIdx.x == 0) {
        s  = red[0][0] + red[0][1] + red[0][2] + red[0][3];
        sq = red[1][0] + red[1][1] + red[1][2] + red[1][3];
        float mean = s * (1.f / 16384.f);
        float var  = sq * (1.f / 16384.f) - mean * mean;
        stats[bg * 2]     = mean;
        stats[bg * 2 + 1] = rsqrtf(var + 1e-5f);
    }
}

// ---------------- K2: normalize + scale/bias + fp16 + transpose -> xnT[b][t][c] ----------------
__global__ void k_gn_apply_t(const float* __restrict__ x, const float* __restrict__ stats,
                             const float* __restrict__ scale, const float* __restrict__ bias,
                             half_t* __restrict__ xnT) {
    int bx = blockIdx.x;            // 16 * 8 * 16
    int b = bx >> 7;
    int r = bx & 127;
    int c0 = (r >> 4) * 64;
    int t0 = (r & 15) * 64;
    __shared__ half_t lds[64][72];
    int ci = threadIdx.x >> 4;          // 0..15
    int tj = (threadIdx.x & 15) * 4;
    for (int p = 0; p < 4; p++) {
        int c = c0 + ci + p * 16;
        float mean = stats[(b * 32 + (c >> 4)) * 2];
        float rsig = stats[(b * 32 + (c >> 4)) * 2 + 1];
        float sc = scale[c] * rsig;
        float bs = bias[c] - mean * sc;
        float4_t v = *(const float4_t*)(x + ((size_t)(b * 512 + c)) * 1024 + t0 + tj);
        half4_t hx;
        for (int j = 0; j < 4; j++) hx[j] = (half_t)(v[j] * sc + bs);
        *(half4_t*)(&lds[ci + p * 16][tj]) = hx;
    }
    __syncthreads();
    int cj = (threadIdx.x & 7) * 8;
    int ti = threadIdx.x >> 3;          // 0..31
    for (int p = 0; p < 2; p++) {
        int t = ti + p * 32;
        half8_t h;
        for (int j = 0; j < 8; j++) h[j] = lds[cj + j][t];
        *(half8_t*)(xnT + ((size_t)(b * 1024 + t0 + t)) * 512 + c0 + cj) = h;
    }
}

// ---------------- K3: QKV GEMM (M/N=128, K=512), gload_lds + swizzle, per-tile output orientation --------
// o-tile in [0,512): Q -> qT[b][h][t][d];  [512,1024): K -> kT[b][h][t][d];  [1024,1536): V -> v[b][o][t]
__global__ __launch_bounds__(256) void k_qkv_gemm(const half_t* __restrict__ xnT,
                                                  const half_t* __restrict__ w16,
                                                  const float* __restrict__ qkv_b,
                                                  half_t* __restrict__ qT,
                                                  half_t* __restrict__ kT,
                                                  half_t* __restrict__ vg) {
    int bx = blockIdx.x;            // 16 * 8 * 12
    int b = bx / 96;
    int r = bx % 96;
    int t0 = (r / 12) * 128;
    int o0 = (r % 12) * 128;
    __shared__ half_t lA[128 * 64];
    __shared__ half_t lB[128 * 64];
    int tid = threadIdx.x;
    int lane = tid & 63, w = tid >> 6;
    int wr = w >> 1, wc = w & 1;
    int l15 = lane & 15, l4 = lane >> 4;
    int srow = lane >> 3;                      // 0..7 within 8-row stripe
    int cs = (lane & 7) ^ srow;                // pre-swizzled global chunk
    const half_t* gA = xnT + ((size_t)(b * 1024) + t0) * 512;
    const half_t* gB = w16 + (size_t)o0 * 512;
    const bool qk = (o0 < 1024);
    f32x4 acc[4][4] = {};
    for (int kk = 0; kk < 512; kk += 64) {
        for (int p = 0; p < 4; p++) {          // wave w stages rows w*32 .. w*32+31
            int row = w * 32 + p * 8;
            gload16(gA + (size_t)(row + srow) * 512 + kk + cs * 8, &lA[row * 64]);
            gload16(gB + (size_t)(row + srow) * 512 + kk + cs * 8, &lB[row * 64]);
        }
        __syncthreads();
        for (int ks = 0; ks < 2; ks++) {
            int colk = ks * 32 + l4 * 8;
            half8_t a[4], bb[4];
            for (int mi = 0; mi < 4; mi++) a[mi]  = *(const half8_t*)swz(lA, wr * 64 + mi * 16 + l15, colk);
            for (int ni = 0; ni < 4; ni++) bb[ni] = *(const half8_t*)swz(lB, wc * 64 + ni * 16 + l15, colk);
            if (qk) {
                for (int mi = 0; mi < 4; mi++)
                    for (int ni = 0; ni < 4; ni++)   // D[o][t]
                        acc[ni][mi] = __builtin_amdgcn_mfma_f32_16x16x32_f16(bb[ni], a[mi], acc[ni][mi], 0, 0, 0);
            } else {
                for (int mi = 0; mi < 4; mi++)
                    for (int ni = 0; ni < 4; ni++)   // D[t][o]
                        acc[mi][ni] = __builtin_amdgcn_mfma_f32_16x16x32_f16(a[mi], bb[ni], acc[mi][ni], 0, 0, 0);
            }
        }
        __syncthreads();
    }
    if (qk) {
        // row = o = o0 + wc*64 + ni*16 + l4*4 + j ; col = t = t0 + wr*64 + mi*16 + l15
        half_t* dstbase = (o0 < 512) ? qT : kT;
        for (int ni = 0; ni < 4; ni++) {
            int obase = o0 + wc * 64 + ni * 16 + l4 * 4;
            int hh = (obase >> 6) & 7;
            int d0 = obase & 63;
            float4_t b4 = *(const float4_t*)(qkv_b + obase);
            half_t* dst = dstbase + ((size_t)(b * 8 + hh) * 1024) * 64 + d0;
            for (int mi = 0; mi < 4; mi++) {
                int t = t0 + wr * 64 + mi * 16 + l15;
                half4_t hv;
                for (int j = 0; j < 4; j++) hv[j] = (half_t)(acc[ni][mi][j] + b4[j]);
                *(half4_t*)(dst + (size_t)t * 64) = hv;
            }
        }
    } else {
        for (int ni = 0; ni < 4; ni++) {
            int oa = o0 + wc * 64 + ni * 16 + l15;       // absolute o
            float bias = qkv_b[oa];
            int ov = oa - 1024;
            for (int mi = 0; mi < 4; mi++) {
                int t = t0 + wr * 64 + mi * 16 + l4 * 4;
                half4_t hv;
                for (int j = 0; j < 4; j++) hv[j] = (half_t)(acc[mi][ni][j] + bias);
                *(half4_t*)(vg + ((size_t)(b * 512) + ov) * 1024 + t) = hv;
            }
        }
    }
}

// ---------------- K4: flash attention per (b,h,t-tile of 64) ----------------
// Q frags direct from global qT; K/V staged via gload_lds (pre-swizzled source,
// swizzled reads), double-buffered with 1-tile prefetch; defer-max softmax.
__global__ __launch_bounds__(256) void k_attn(const half_t* __restrict__ qT,
                                              const half_t* __restrict__ kT,
                                              const half_t* __restrict__ vg,
                                              half_t* __restrict__ aT) {
    int bx = blockIdx.x;            // 128 * 16
    int bh = bx >> 4;
    int t0 = (bx & 15) * 64;
    int b = bh >> 3, h = bh & 7;
    const half_t* kbase = kT + (size_t)bh * 1024 * 64;                 // [s][d]
    const half_t* vbase = vg + ((size_t)(b * 512 + h * 64)) * 1024;   // [d][t]

    __shared__ half_t lK[2][64 * 64];
    __shared__ half_t lV[2][64 * 64];
    __shared__ half_t smp[4][16 * 64];   // per-wave P[t][s], swizzled

    int tid = threadIdx.x;
    int lane = tid & 63, w = tid >> 6;
    int l15 = lane & 15, l4 = lane >> 4;
    const float SC = 0.18033688f;        // 0.125 * log2(e)

    int srow = tid >> 3;                 // 0..31
    int cs = (tid & 7) ^ (srow & 7);     // pre-swizzled source chunk

    // stage K-tile and V-tile (8KB each) for s-tile starting at s0 into buffer buf
    auto stage = [&](int buf, int s0) {
        #pragma unroll
        for (int rr = 0; rr < 2; rr++) {
            int row = rr * 32 + srow;
            gload16(kbase + (size_t)(s0 + row) * 64 + cs * 8, &lK[buf][(rr * 256 + w * 64) * 8]);
            gload16(vbase + (size_t)row * 1024 + s0 + cs * 8, &lV[buf][(rr * 256 + w * 64) * 8]);
        }
    };

    // Q B-frags direct from global (pre-scaled into exp2 domain)
    half8_t bq[2];
    {
        const half_t* qrow = qT + ((size_t)bh * 1024 + t0 + w * 16 + l15) * 64;
        for (int ks = 0; ks < 2; ks++) {
            half8_t raw = *(const half8_t*)(qrow + ks * 32 + l4 * 8);
            for (int j = 0; j < 8; j++) bq[ks][j] = (half_t)((float)raw[j] * SC);
        }
    }

    half_t* pw = smp[w];
    f32x4 oacc[4] = {};
    float m_ = -1e30f, l_ = 0.f;

    stage(0, 0);
    asm volatile("s_waitcnt vmcnt(0)" ::: "memory");
    __syncthreads();

    int cur = 0;
    for (int it = 0; it < 16; it++) {
        if (it < 15) stage(cur ^ 1, (it + 1) * 64);   // prefetch next tile (overlaps compute)
        // S^T tile (exp2 domain): st[ni][r] = S2[s-row][q-col=l15]
        f32x4 st[4] = {};
        __builtin_amdgcn_s_setprio(1);
        for (int ks = 0; ks < 2; ks++) {
            int colk = ks * 32 + l4 * 8;
            for (int ni = 0; ni < 4; ni++) {
                half8_t ak = *(const half8_t*)swz(&lK[cur][0], ni * 16 + l15, colk);
                st[ni] = __builtin_amdgcn_mfma_f32_16x16x32_f16(ak, bq[ks], st[ni], 0, 0, 0);
            }
        }
        __builtin_amdgcn_s_setprio(0);
        // lane-local max over 16 s-values + 2-step cross-group reduce
        float tm = st[0][0];
        for (int ni = 0; ni < 4; ni++)
            for (int rr = 0; rr < 4; rr++) tm = fmaxf(tm, st[ni][rr]);
        tm = fmaxf(tm, __shfl_xor(tm, 16, 64));
        tm = fmaxf(tm, __shfl_xor(tm, 32, 64));
        // defer-max: rescale O only when running max grew by > 8 (P bounded by 2^8)
        if (__any(tm > m_ + 8.0f)) {
            float nm = fmaxf(m_, tm);
            float f = exp2f(m_ - nm);
            l_ *= f;
            for (int mi = 0; mi < 4; mi++)
                for (int i = 0; i < 4; i++) oacc[mi][i] *= f;
            m_ = nm;
        }
        float ps = 0.f;
        for (int ni = 0; ni < 4; ni++) {
            half4_t ph;
            for (int rr = 0; rr < 4; rr++) {
                float p = exp2f(st[ni][rr] - m_);
                ps += p;
                ph[rr] = (half_t)p;
            }
            *(half4_t*)swz(pw, l15, ni * 16 + l4 * 4) = ph;   // P[t][s]
        }
        ps += __shfl_xor(ps, 16, 64);
        ps += __shfl_xor(ps, 32, 64);
        l_ += ps;
        // O += V P^T : A = lV[d][s], B[k=s][col=t] = P rows
        __builtin_amdgcn_s_setprio(1);
        for (int ks = 0; ks < 2; ks++) {
            int colk = ks * 32 + l4 * 8;
            half8_t bp = *(const half8_t*)swz(pw, l15, colk);
            for (int mi = 0; mi < 4; mi++) {
                half8_t av = *(const half8_t*)swz(&lV[cur][0], mi * 16 + l15, colk);
                oacc[mi] = __builtin_amdgcn_mfma_f32_16x16x32_f16(av, bp, oacc[mi], 0, 0, 0);
            }
        }
        __builtin_amdgcn_s_setprio(0);
        asm volatile("s_waitcnt vmcnt(0)" ::: "memory");   // prefetch landed
        __syncthreads();                                   // publish; all waves done with cur
        cur ^= 1;
    }
    // O /= l ; store aT[b][t][h*64+d]  (col t = l15 lane-local, rows d = mi*16+l4*4+i)
    float linv = 1.0f / l_;
    int t = t0 + w * 16 + l15;
    for (int mi = 0; mi < 4; mi++) {
        half4_t hv;
        for (int i = 0; i < 4; i++) hv[i] = (half_t)(oacc[mi][i] * linv);
        *(half4_t*)(aT + ((size_t)(b * 1024) + t) * 512 + h * 64 + mi * 16 + l4 * 4) = hv;
    }
}

// ---------------- K5: proj GEMM + bias + residual  (M=t, N=o, K=c), gload_lds + swizzle ----------------
__global__ __launch_bounds__(256) void k_proj_gemm(const half_t* __restrict__ aT,
                                                   const half_t* __restrict__ pw16,
                                                   const float* __restrict__ proj_b,
                                                   const float* __restrict__ x,
                                                   float* __restrict__ out) {
    int bx = blockIdx.x;            // 16 * 8 * 4
    int b = bx / 32;
    int r = bx % 32;
    int t0 = (r / 4) * 128;
    int o0 = (r % 4) * 128;
    __shared__ half_t lA[128 * 64];
    __shared__ half_t lB[128 * 64];
    int tid = threadIdx.x;
    int lane = tid & 63, w = tid >> 6;
    int wr = w >> 1, wc = w & 1;
    int l15 = lane & 15, l4 = lane >> 4;
    int srow = lane >> 3;
    int cs = (lane & 7) ^ srow;
    const half_t* gA = aT + ((size_t)(b * 1024) + t0) * 512;
    const half_t* gB = pw16 + (size_t)o0 * 512;
    f32x4 acc[4][4] = {};
    for (int kk = 0; kk < 512; kk += 64) {
        for (int p = 0; p < 4; p++) {
            int row = w * 32 + p * 8;
            gload16(gA + (size_t)(row + srow) * 512 + kk + cs * 8, &lA[row * 64]);
            gload16(gB + (size_t)(row + srow) * 512 + kk + cs * 8, &lB[row * 64]);
        }
        __syncthreads();
        for (int ks = 0; ks < 2; ks++) {
            int colk = ks * 32 + l4 * 8;
            half8_t a[4], bb[4];
            for (int mi = 0; mi < 4; mi++) a[mi]  = *(const half8_t*)swz(lA, wr * 64 + mi * 16 + l15, colk);
            for (int ni = 0; ni < 4; ni++) bb[ni] = *(const half8_t*)swz(lB, wc * 64 + ni * 16 + l15, colk);
            for (int mi = 0; mi < 4; mi++)
                for (int ni = 0; ni < 4; ni++)
                    acc[mi][ni] = __builtin_amdgcn_mfma_f32_16x16x32_f16(a[mi], bb[ni], acc[mi][ni], 0, 0, 0);
        }
        __syncthreads();
    }
    for (int ni = 0; ni < 4; ni++) {
        int o = o0 + wc * 64 + ni * 16 + l15;
        float bias = proj_b[o];
        for (int mi = 0; mi < 4; mi++) {
            int t = t0 + wr * 64 + mi * 16 + l4 * 4;
            size_t idx = ((size_t)(b * 512) + o) * 1024 + t;
            float4_t xres = *(const float4_t*)(x + idx);
            float4_t ov;
            for (int j = 0; j < 4; j++) ov[j] = acc[mi][ni][j] + bias + xres[j];
            *(float4_t*)(out + idx) = ov;
        }
    }
}

extern "C" void kernel_launch(void* const* d_in, const int* in_sizes, int n_in,
                              void* d_out, int out_size, void* d_ws, size_t ws_size,
                              hipStream_t stream) {
    const float* x        = (const float*)d_in[0];
    const float* gn_scale = (const float*)d_in[1];
    const float* gn_bias  = (const float*)d_in[2];
    const float* qkv_w    = (const float*)d_in[3];
    const float* qkv_b    = (const float*)d_in[4];
    const float* proj_w   = (const float*)d_in[5];
    const float* proj_b   = (const float*)d_in[6];
    float* out = (float*)d_out;

    char* ws = (char*)d_ws;
    half_t* w16  = (half_t*)(ws + OFF_W16);
    half_t* pw16 = (half_t*)(ws + OFF_PW16);
    half_t* xnT  = (half_t*)(ws + OFF_XNT);
    half_t* qTp  = (half_t*)(ws + OFF_QT);
    half_t* kTp  = (half_t*)(ws + OFF_KT);
    half_t* vp   = (half_t*)(ws + OFF_V);
    half_t* aT   = (half_t*)(ws + OFF_AT);
    float*  stat = (float*) (ws + OFF_STAT);

    k_convert_w<<<1024, 256, 0, stream>>>(qkv_w, proj_w, w16, pw16);
    k_gn_stats<<<512, 256, 0, stream>>>(x, stat);
    k_gn_apply_t<<<2048, 256, 0, stream>>>(x, stat, gn_scale, gn_bias, xnT);
    k_qkv_gemm<<<1536, 256, 0, stream>>>(xnT, w16, qkv_b, qTp, kTp, vp);
    k_attn<<<2048, 256, 0, stream>>>(qTp, kTp, vp, aT);
    k_proj_gemm<<<512, 256, 0, stream>>>(aT, pw16, proj_b, x, out);
}

// Round 6
// 257.145 us; speedup vs baseline: 1.2058x; 1.0043x over previous
//
#include <hip/hip_runtime.h>

typedef _Float16 half_t;
typedef __fp16 fp16x2_t __attribute__((ext_vector_type(2)));
typedef _Float16 half2_t __attribute__((ext_vector_type(2)));
typedef _Float16 half4_t __attribute__((ext_vector_type(4)));
typedef _Float16 half8_t __attribute__((ext_vector_type(8)));
typedef float f32x4 __attribute__((ext_vector_type(4)));
typedef float float4_t __attribute__((ext_vector_type(4)));

#define NB 16
#define NC 512
#define NT 1024
#define NHEAD 8
#define DH 64

// ---------------- workspace layout (bytes) ----------------
#define OFF_W16  ((size_t)0)                                  // qkv_w fp16 [1536][512]
#define OFF_PW16 (OFF_W16  + (size_t)1536*512*2)              // proj_w fp16 [512][512]
#define OFF_XNT  (OFF_PW16 + (size_t)512*512*2)               // xnT fp16 [16][1024][512]
#define OFF_QT   (OFF_XNT  + (size_t)16*1024*512*2)           // qT  fp16 [16][8][1024][64]
#define OFF_KT   (OFF_QT   + (size_t)16*8*1024*64*2)          // kT  fp16 [16][8][1024][64]
#define OFF_V    (OFF_KT   + (size_t)16*8*1024*64*2)          // v   fp16 [16][512][1024]
#define OFF_AT   (OFF_V    + (size_t)16*512*1024*2)           // aT  fp16 [16][1024][512]
#define OFF_STAT (OFF_AT   + (size_t)16*1024*512*2)           // stats f32 [16][32][2]

// async global->LDS, 16B per lane; LDS dest = wave-uniform base + lane*16
__device__ __forceinline__ void gload16(const half_t* g, half_t* l) {
    __builtin_amdgcn_global_load_lds(
        (const __attribute__((address_space(1))) void*)g,
        (__attribute__((address_space(3))) void*)l, 16, 0, 0);
}

// XOR-swizzled LDS address for tiles with 128B row stride:
// byte = (row*128 + col*2) ^ ((row&7)<<4); 16B-chunk-preserving, bijective.
__device__ __forceinline__ half_t* swz(half_t* base, int row, int col) {
    int byte = ((row << 7) + (col << 1)) ^ ((row & 7) << 4);
    return (half_t*)((char*)base + byte);
}

// packed f32x2 -> f16x2 (rtz)
__device__ __forceinline__ half2_t pk16(float a, float b) {
    fp16x2_t r = __builtin_amdgcn_cvt_pkrtz(a, b);
    return __builtin_bit_cast(half2_t, r);
}

// ---------------- K0: weights fp32 -> fp16 ----------------
__global__ void k_convert_w(const float* __restrict__ qkv_w, const float* __restrict__ proj_w,
                            half_t* __restrict__ w16, half_t* __restrict__ pw16) {
    int i = (blockIdx.x * 256 + threadIdx.x) * 4;
    const int NQ = 1536 * 512;
    if (i < NQ) {
        float4_t v = *(const float4_t*)(qkv_w + i);
        half4_t h; for (int j = 0; j < 4; j++) h[j] = (half_t)v[j];
        *(half4_t*)(w16 + i) = h;
    } else {
        int k = i - NQ;
        float4_t v = *(const float4_t*)(proj_w + k);
        half4_t h; for (int j = 0; j < 4; j++) h[j] = (half_t)v[j];
        *(half4_t*)(pw16 + k) = h;
    }
}

// ---------------- K1: per-(b,group) mean / rsigma ----------------
__global__ void k_gn_stats(const float* __restrict__ x, float* __restrict__ stats) {
    int bg = blockIdx.x;                       // b*32+g ; group = 16 ch * 1024 contiguous floats
    const float* p = x + (size_t)bg * 16384;
    float s = 0.f, sq = 0.f;
    for (int i = threadIdx.x; i < 4096; i += 256) {
        float4_t v = *(const float4_t*)(p + i * 4);
        for (int j = 0; j < 4; j++) { s += v[j]; sq += v[j] * v[j]; }
    }
    for (int m = 1; m < 64; m <<= 1) { s += __shfl_xor(s, m, 64); sq += __shfl_xor(sq, m, 64); }
    __shared__ float red[2][4];
    int wid = threadIdx.x >> 6;
    if ((threadIdx.x & 63) == 0) { red[0][wid] = s; red[1][wid] = sq; }
    __syncthreads();
    if (threadIdx.x == 0) {
        s  = red[0][0] + red[0][1] + red[0][2] + red[0][3];
        sq = red[1][0] + red[1][1] + red[1][2] + red[1][3];
        float mean = s * (1.f / 16384.f);
        float var  = sq * (1.f / 16384.f) - mean * mean;
        stats[bg * 2]     = mean;
        stats[bg * 2 + 1] = rsqrtf(var + 1e-5f);
    }
}

// ---------------- K2: normalize + scale/bias + fp16 + transpose -> xnT[b][t][c] ----------------
__global__ void k_gn_apply_t(const float* __restrict__ x, const float* __restrict__ stats,
                             const float* __restrict__ scale, const float* __restrict__ bias,
                             half_t* __restrict__ xnT) {
    int bx = blockIdx.x;            // 16 * 8 * 16
    int b = bx >> 7;
    int r = bx & 127;
    int c0 = (r >> 4) * 64;
    int t0 = (r & 15) * 64;
    __shared__ half_t lds[64][72];
    int ci = threadIdx.x >> 4;          // 0..15
    int tj = (threadIdx.x & 15) * 4;
    for (int p = 0; p < 4; p++) {
        int c = c0 + ci + p * 16;
        float mean = stats[(b * 32 + (c >> 4)) * 2];
        float rsig = stats[(b * 32 + (c >> 4)) * 2 + 1];
        float sc = scale[c] * rsig;
        float bs = bias[c] - mean * sc;
        float4_t v = *(const float4_t*)(x + ((size_t)(b * 512 + c)) * 1024 + t0 + tj);
        half4_t hx;
        for (int j = 0; j < 4; j++) hx[j] = (half_t)(v[j] * sc + bs);
        *(half4_t*)(&lds[ci + p * 16][tj]) = hx;
    }
    __syncthreads();
    int cj = (threadIdx.x & 7) * 8;
    int ti = threadIdx.x >> 3;          // 0..31
    for (int p = 0; p < 2; p++) {
        int t = ti + p * 32;
        half8_t h;
        for (int j = 0; j < 8; j++) h[j] = lds[cj + j][t];
        *(half8_t*)(xnT + ((size_t)(b * 1024 + t0 + t)) * 512 + c0 + cj) = h;
    }
}

// ---------------- K3: QKV GEMM (M=256, N=128, K=512), 8 waves, gload_lds + swizzle ----------------
// o-tile in [0,512): Q -> qT[b][h][t][d];  [512,1024): K -> kT[b][h][t][d];  [1024,1536): V -> v[b][o][t]
__global__ __launch_bounds__(512) void k_qkv_gemm(const half_t* __restrict__ xnT,
                                                  const half_t* __restrict__ w16,
                                                  const float* __restrict__ qkv_b,
                                                  half_t* __restrict__ qT,
                                                  half_t* __restrict__ kT,
                                                  half_t* __restrict__ vg) {
    int bx = blockIdx.x;            // 16 * 4 * 12 = 768
    int b = bx / 48;
    int r = bx % 48;
    int t0 = (r / 12) * 256;
    int o0 = (r % 12) * 128;
    __shared__ half_t lA[256 * 64];
    __shared__ half_t lB[128 * 64];
    int tid = threadIdx.x;
    int lane = tid & 63, w = tid >> 6;       // 8 waves: 4(m) x 2(n)
    int wr = w >> 1, wc = w & 1;
    int l15 = lane & 15, l4 = lane >> 4;
    int srow = lane >> 3;                    // 0..7 within 8-row stripe
    int cs = (lane & 7) ^ srow;              // pre-swizzled global chunk
    const half_t* gA = xnT + ((size_t)(b * 1024) + t0) * 512;
    const half_t* gB = w16 + (size_t)o0 * 512;
    const bool qk = (o0 < 1024);
    f32x4 acc[4][4] = {};
    for (int kk = 0; kk < 512; kk += 64) {
        for (int p = 0; p < 4; p++) {        // wave w stages A rows w*32 .. w*32+31
            int row = w * 32 + p * 8;
            gload16(gA + (size_t)(row + srow) * 512 + kk + cs * 8, &lA[row * 64]);
        }
        for (int p = 0; p < 2; p++) {        // wave w stages B rows w*16 .. w*16+15
            int row = w * 16 + p * 8;
            gload16(gB + (size_t)(row + srow) * 512 + kk + cs * 8, &lB[row * 64]);
        }
        __syncthreads();
        for (int ks = 0; ks < 2; ks++) {
            int colk = ks * 32 + l4 * 8;
            half8_t a[4], bb[4];
            for (int mi = 0; mi < 4; mi++) a[mi]  = *(const half8_t*)swz(lA, wr * 64 + mi * 16 + l15, colk);
            for (int ni = 0; ni < 4; ni++) bb[ni] = *(const half8_t*)swz(lB, wc * 64 + ni * 16 + l15, colk);
            if (qk) {
                for (int mi = 0; mi < 4; mi++)
                    for (int ni = 0; ni < 4; ni++)   // D[o][t]
                        acc[ni][mi] = __builtin_amdgcn_mfma_f32_16x16x32_f16(bb[ni], a[mi], acc[ni][mi], 0, 0, 0);
            } else {
                for (int mi = 0; mi < 4; mi++)
                    for (int ni = 0; ni < 4; ni++)   // D[t][o]
                        acc[mi][ni] = __builtin_amdgcn_mfma_f32_16x16x32_f16(a[mi], bb[ni], acc[mi][ni], 0, 0, 0);
            }
        }
        __syncthreads();
    }
    if (qk) {
        // row = o = o0 + wc*64 + ni*16 + l4*4 + j ; col = t = t0 + wr*64 + mi*16 + l15
        half_t* dstbase = (o0 < 512) ? qT : kT;
        for (int ni = 0; ni < 4; ni++) {
            int obase = o0 + wc * 64 + ni * 16 + l4 * 4;
            int hh = (obase >> 6) & 7;
            int d0 = obase & 63;
            float4_t b4 = *(const float4_t*)(qkv_b + obase);
            half_t* dst = dstbase + ((size_t)(b * 8 + hh) * 1024) * 64 + d0;
            for (int mi = 0; mi < 4; mi++) {
                int t = t0 + wr * 64 + mi * 16 + l15;
                half4_t hv;
                for (int j = 0; j < 4; j++) hv[j] = (half_t)(acc[ni][mi][j] + b4[j]);
                *(half4_t*)(dst + (size_t)t * 64) = hv;
            }
        }
    } else {
        for (int ni = 0; ni < 4; ni++) {
            int oa = o0 + wc * 64 + ni * 16 + l15;       // absolute o
            float bias = qkv_b[oa];
            int ov = oa - 1024;
            for (int mi = 0; mi < 4; mi++) {
                int t = t0 + wr * 64 + mi * 16 + l4 * 4;
                half4_t hv;
                for (int j = 0; j < 4; j++) hv[j] = (half_t)(acc[mi][ni][j] + bias);
                *(half4_t*)(vg + ((size_t)(b * 512) + ov) * 1024 + t) = hv;
            }
        }
    }
}

// ---------------- K4: flash attention per (b,h,t-tile of 64) ----------------
// Q frags direct from global; K/V double-buffered via gload_lds with STATIC buffer
// names (unroll x2) so all swizzled LDS addresses fold to per-lane consts + imm offsets.
__global__ __launch_bounds__(256) void k_attn(const half_t* __restrict__ qT,
                                              const half_t* __restrict__ kT,
                                              const half_t* __restrict__ vg,
                                              half_t* __restrict__ aT) {
    int bx = blockIdx.x;            // 128 * 16
    int bh = bx >> 4;
    int t0 = (bx & 15) * 64;
    int b = bh >> 3, h = bh & 7;
    const half_t* kbase = kT + (size_t)bh * 1024 * 64;                // [s][d]
    const half_t* vbase = vg + ((size_t)(b * 512 + h * 64)) * 1024;  // [d][t]

    __shared__ half_t lK0[64 * 64], lK1[64 * 64];
    __shared__ half_t lV0[64 * 64], lV1[64 * 64];
    __shared__ half_t smp[4][16 * 64];   // per-wave P[t][s], swizzled

    int tid = threadIdx.x;
    int lane = tid & 63, w = tid >> 6;
    int l15 = lane & 15, l4 = lane >> 4;
    const float SC = 0.18033688f;        // 0.125 * log2(e)

    int srow = tid >> 3;                 // 0..31
    int cs = (tid & 7) ^ (srow & 7);     // pre-swizzled source chunk

    auto stage = [&](half_t* K, half_t* V, int s0) {
        #pragma unroll
        for (int rr = 0; rr < 2; rr++) {
            int row = rr * 32 + srow;
            gload16(kbase + (size_t)(s0 + row) * 64 + cs * 8, &K[(rr * 256 + w * 64) * 8]);
            gload16(vbase + (size_t)row * 1024 + s0 + cs * 8, &V[(rr * 256 + w * 64) * 8]);
        }
    };

    // Q B-frags direct from global (pre-scaled into exp2 domain)
    half8_t bq[2];
    {
        const half_t* qrow = qT + ((size_t)bh * 1024 + t0 + w * 16 + l15) * 64;
        for (int ks = 0; ks < 2; ks++) {
            half8_t raw = *(const half8_t*)(qrow + ks * 32 + l4 * 8);
            for (int j = 0; j < 8; j++) bq[ks][j] = (half_t)((float)raw[j] * SC);
        }
    }

    half_t* pw = smp[w];
    f32x4 oacc[4] = {};
    float m_ = -1e30f, l_ = 0.f;

    auto do_iter = [&](int it, half_t* Kc, half_t* Vc, half_t* Kn, half_t* Vn, bool pf) {
        if (pf) stage(Kn, Vn, (it + 1) * 64);
        // S^T tile (exp2 domain): st[ni][r] = S2[s-row][q-col=l15]
        f32x4 st[4] = {};
        __builtin_amdgcn_s_setprio(1);
        #pragma unroll
        for (int ks = 0; ks < 2; ks++) {
            int colk = ks * 32 + l4 * 8;
            #pragma unroll
            for (int ni = 0; ni < 4; ni++) {
                half8_t ak = *(const half8_t*)swz(Kc, ni * 16 + l15, colk);
                st[ni] = __builtin_amdgcn_mfma_f32_16x16x32_f16(ak, bq[ks], st[ni], 0, 0, 0);
            }
        }
        __builtin_amdgcn_s_setprio(0);
        // lane-local max over 16 s-values + 2-step cross-group reduce
        float tm = st[0][0];
        #pragma unroll
        for (int ni = 0; ni < 4; ni++)
            for (int rr = 0; rr < 4; rr++) tm = fmaxf(tm, st[ni][rr]);
        tm = fmaxf(tm, __shfl_xor(tm, 16, 64));
        tm = fmaxf(tm, __shfl_xor(tm, 32, 64));
        // defer-max: rescale O only when running max grew by > 8 (P bounded by 2^8)
        if (__any(tm > m_ + 8.0f)) {
            float nm = fmaxf(m_, tm);
            float f = exp2f(m_ - nm);
            l_ *= f;
            #pragma unroll
            for (int mi = 0; mi < 4; mi++)
                for (int i = 0; i < 4; i++) oacc[mi][i] *= f;
            m_ = nm;
        }
        float ps = 0.f;
        #pragma unroll
        for (int ni = 0; ni < 4; ni++) {
            float p0 = exp2f(st[ni][0] - m_), p1 = exp2f(st[ni][1] - m_);
            float p2 = exp2f(st[ni][2] - m_), p3 = exp2f(st[ni][3] - m_);
            ps += (p0 + p1) + (p2 + p3);
            half2_t lo = pk16(p0, p1);
            half2_t hi = pk16(p2, p3);
            half4_t ph = {lo[0], lo[1], hi[0], hi[1]};
            *(half4_t*)swz(pw, l15, ni * 16 + l4 * 4) = ph;   // P[t][s]
        }
        ps += __shfl_xor(ps, 16, 64);
        ps += __shfl_xor(ps, 32, 64);
        l_ += ps;
        // O += V P^T : A = V[d][s], B[k=s][col=t] = P rows
        __builtin_amdgcn_s_setprio(1);
        #pragma unroll
        for (int ks = 0; ks < 2; ks++) {
            int colk = ks * 32 + l4 * 8;
            half8_t bp = *(const half8_t*)swz(pw, l15, colk);
            #pragma unroll
            for (int mi = 0; mi < 4; mi++) {
                half8_t av = *(const half8_t*)swz(Vc, mi * 16 + l15, colk);
                oacc[mi] = __builtin_amdgcn_mfma_f32_16x16x32_f16(av, bp, oacc[mi], 0, 0, 0);
            }
        }
        __builtin_amdgcn_s_setprio(0);
        asm volatile("s_waitcnt vmcnt(0)" ::: "memory");   // prefetch landed
        __syncthreads();                                   // publish; all waves done with cur
    };

    stage(lK0, lV0, 0);
    asm volatile("s_waitcnt vmcnt(0)" ::: "memory");
    __syncthreads();

    for (int hh = 0; hh < 8; hh++) {
        do_iter(2 * hh,     lK0, lV0, lK1, lV1, true);
        do_iter(2 * hh + 1, lK1, lV1, lK0, lV0, hh < 7);
    }

    // O /= l ; store aT[b][t][h*64+d]  (col t = l15 lane-local, rows d = mi*16+l4*4+i)
    float linv = 1.0f / l_;
    int t = t0 + w * 16 + l15;
    for (int mi = 0; mi < 4; mi++) {
        half4_t hv;
        for (int i = 0; i < 4; i++) hv[i] = (half_t)(oacc[mi][i] * linv);
        *(half4_t*)(aT + ((size_t)(b * 1024) + t) * 512 + h * 64 + mi * 16 + l4 * 4) = hv;
    }
}

// ---------------- K5: proj GEMM + bias + residual (M=256, N=128, K=512), 8 waves ----------------
__global__ __launch_bounds__(512) void k_proj_gemm(const half_t* __restrict__ aT,
                                                   const half_t* __restrict__ pw16,
                                                   const float* __restrict__ proj_b,
                                                   const float* __restrict__ x,
                                                   float* __restrict__ out) {
    int bx = blockIdx.x;            // 16 * 4 * 4 = 256
    int b = bx / 16;
    int r = bx % 16;
    int t0 = (r / 4) * 256;
    int o0 = (r % 4) * 128;
    __shared__ half_t lA[256 * 64];
    __shared__ half_t lB[128 * 64];
    int tid = threadIdx.x;
    int lane = tid & 63, w = tid >> 6;
    int wr = w >> 1, wc = w & 1;
    int l15 = lane & 15, l4 = lane >> 4;
    int srow = lane >> 3;
    int cs = (lane & 7) ^ srow;
    const half_t* gA = aT + ((size_t)(b * 1024) + t0) * 512;
    const half_t* gB = pw16 + (size_t)o0 * 512;
    f32x4 acc[4][4] = {};
    for (int kk = 0; kk < 512; kk += 64) {
        for (int p = 0; p < 4; p++) {
            int row = w * 32 + p * 8;
            gload16(gA + (size_t)(row + srow) * 512 + kk + cs * 8, &lA[row * 64]);
        }
        for (int p = 0; p < 2; p++) {
            int row = w * 16 + p * 8;
            gload16(gB + (size_t)(row + srow) * 512 + kk + cs * 8, &lB[row * 64]);
        }
        __syncthreads();
        for (int ks = 0; ks < 2; ks++) {
            int colk = ks * 32 + l4 * 8;
            half8_t a[4], bb[4];
            for (int mi = 0; mi < 4; mi++) a[mi]  = *(const half8_t*)swz(lA, wr * 64 + mi * 16 + l15, colk);
            for (int ni = 0; ni < 4; ni++) bb[ni] = *(const half8_t*)swz(lB, wc * 64 + ni * 16 + l15, colk);
            for (int mi = 0; mi < 4; mi++)
                for (int ni = 0; ni < 4; ni++)
                    acc[mi][ni] = __builtin_amdgcn_mfma_f32_16x16x32_f16(a[mi], bb[ni], acc[mi][ni], 0, 0, 0);
        }
        __syncthreads();
    }
    for (int ni = 0; ni < 4; ni++) {
        int o = o0 + wc * 64 + ni * 16 + l15;
        float bias = proj_b[o];
        for (int mi = 0; mi < 4; mi++) {
            int t = t0 + wr * 64 + mi * 16 + l4 * 4;
            size_t idx = ((size_t)(b * 512) + o) * 1024 + t;
            float4_t xres = *(const float4_t*)(x + idx);
            float4_t ov;
            for (int j = 0; j < 4; j++) ov[j] = acc[mi][ni][j] + bias + xres[j];
            *(float4_t*)(out + idx) = ov;
        }
    }
}

extern "C" void kernel_launch(void* const* d_in, const int* in_sizes, int n_in,
                              void* d_out, int out_size, void* d_ws, size_t ws_size,
                              hipStream_t stream) {
    const float* x        = (const float*)d_in[0];
    const float* gn_scale = (const float*)d_in[1];
    const float* gn_bias  = (const float*)d_in[2];
    const float* qkv_w    = (const float*)d_in[3];
    const float* qkv_b    = (const float*)d_in[4];
    const float* proj_w   = (const float*)d_in[5];
    const float* proj_b   = (const float*)d_in[6];
    float* out = (float*)d_out;

    char* ws = (char*)d_ws;
    half_t* w16  = (half_t*)(ws + OFF_W16);
    half_t* pw16 = (half_t*)(ws + OFF_PW16);
    half_t* xnT  = (half_t*)(ws + OFF_XNT);
    half_t* qTp  = (half_t*)(ws + OFF_QT);
    half_t* kTp  = (half_t*)(ws + OFF_KT);
    half_t* vp   = (half_t*)(ws + OFF_V);
    half_t* aT   = (half_t*)(ws + OFF_AT);
    float*  stat = (float*) (ws + OFF_STAT);

    k_convert_w<<<1024, 256, 0, stream>>>(qkv_w, proj_w, w16, pw16);
    k_gn_stats<<<512, 256, 0, stream>>>(x, stat);
    k_gn_apply_t<<<2048, 256, 0, stream>>>(x, stat, gn_scale, gn_bias, xnT);
    k_qkv_gemm<<<768, 512, 0, stream>>>(xnT, w16, qkv_b, qTp, kTp, vp);
    k_attn<<<2048, 256, 0, stream>>>(qTp, kTp, vp, aT);
    k_proj_gemm<<<256, 512, 0, stream>>>(aT, pw16, proj_b, x, out);
}

// Round 7
// 251.252 us; speedup vs baseline: 1.2341x; 1.0235x over previous
//
#include <hip/hip_runtime.h>

typedef _Float16 half_t;
typedef __fp16 fp16x2_t __attribute__((ext_vector_type(2)));
typedef _Float16 half2_t __attribute__((ext_vector_type(2)));
typedef _Float16 half4_t __attribute__((ext_vector_type(4)));
typedef _Float16 half8_t __attribute__((ext_vector_type(8)));
typedef float f32x4 __attribute__((ext_vector_type(4)));
typedef float float4_t __attribute__((ext_vector_type(4)));

#define NB 16
#define NC 512
#define NT 1024
#define NHEAD 8
#define DH 64

// ---------------- workspace layout (bytes) ----------------
#define OFF_W16  ((size_t)0)                                  // qkv_w fp16 [1536][512]
#define OFF_PW16 (OFF_W16  + (size_t)1536*512*2)              // proj_w fp16 [512][512]
#define OFF_XNT  (OFF_PW16 + (size_t)512*512*2)               // xnT fp16 [16][1024][512]
#define OFF_QT   (OFF_XNT  + (size_t)16*1024*512*2)           // qT  fp16 [16][8][1024][64]
#define OFF_KT   (OFF_QT   + (size_t)16*8*1024*64*2)          // kT  fp16 [16][8][1024][64]
#define OFF_V    (OFF_KT   + (size_t)16*8*1024*64*2)          // v   fp16 [16][512][1024]
#define OFF_AT   (OFF_V    + (size_t)16*512*1024*2)           // aT  fp16 [16][1024][512]
#define OFF_STAT (OFF_AT   + (size_t)16*1024*512*2)           // stats f32 [16][32][2]

// async global->LDS, 16B per lane; LDS dest = wave-uniform base + lane*16
__device__ __forceinline__ void gload16(const half_t* g, half_t* l) {
    __builtin_amdgcn_global_load_lds(
        (const __attribute__((address_space(1))) void*)g,
        (__attribute__((address_space(3))) void*)l, 16, 0, 0);
}

// XOR-swizzled LDS address for tiles with 128B row stride:
// byte = (row*128 + col*2) ^ ((row&7)<<4); 16B-chunk-preserving, bijective.
__device__ __forceinline__ half_t* swz(half_t* base, int row, int col) {
    int byte = ((row << 7) + (col << 1)) ^ ((row & 7) << 4);
    return (half_t*)((char*)base + byte);
}

// packed f32x2 -> f16x2 (rtz)
__device__ __forceinline__ half2_t pk16(float a, float b) {
    fp16x2_t r = __builtin_amdgcn_cvt_pkrtz(a, b);
    return __builtin_bit_cast(half2_t, r);
}

// ---------------- K0: weights fp32 -> fp16 ----------------
__global__ void k_convert_w(const float* __restrict__ qkv_w, const float* __restrict__ proj_w,
                            half_t* __restrict__ w16, half_t* __restrict__ pw16) {
    int i = (blockIdx.x * 256 + threadIdx.x) * 4;
    const int NQ = 1536 * 512;
    if (i < NQ) {
        float4_t v = *(const float4_t*)(qkv_w + i);
        half4_t h; for (int j = 0; j < 4; j++) h[j] = (half_t)v[j];
        *(half4_t*)(w16 + i) = h;
    } else {
        int k = i - NQ;
        float4_t v = *(const float4_t*)(proj_w + k);
        half4_t h; for (int j = 0; j < 4; j++) h[j] = (half_t)v[j];
        *(half4_t*)(pw16 + k) = h;
    }
}

// ---------------- K1: per-(b,group) mean / rsigma ----------------
__global__ void k_gn_stats(const float* __restrict__ x, float* __restrict__ stats) {
    int bg = blockIdx.x;                       // b*32+g ; group = 16 ch * 1024 contiguous floats
    const float* p = x + (size_t)bg * 16384;
    float s = 0.f, sq = 0.f;
    for (int i = threadIdx.x; i < 4096; i += 256) {
        float4_t v = *(const float4_t*)(p + i * 4);
        for (int j = 0; j < 4; j++) { s += v[j]; sq += v[j] * v[j]; }
    }
    for (int m = 1; m < 64; m <<= 1) { s += __shfl_xor(s, m, 64); sq += __shfl_xor(sq, m, 64); }
    __shared__ float red[2][4];
    int wid = threadIdx.x >> 6;
    if ((threadIdx.x & 63) == 0) { red[0][wid] = s; red[1][wid] = sq; }
    __syncthreads();
    if (threadIdx.x == 0) {
        s  = red[0][0] + red[0][1] + red[0][2] + red[0][3];
        sq = red[1][0] + red[1][1] + red[1][2] + red[1][3];
        float mean = s * (1.f / 16384.f);
        float var  = sq * (1.f / 16384.f) - mean * mean;
        stats[bg * 2]     = mean;
        stats[bg * 2 + 1] = rsqrtf(var + 1e-5f);
    }
}

// ---------------- K2: normalize + scale/bias + fp16 + transpose -> xnT[b][t][c] ----------------
__global__ void k_gn_apply_t(const float* __restrict__ x, const float* __restrict__ stats,
                             const float* __restrict__ scale, const float* __restrict__ bias,
                             half_t* __restrict__ xnT) {
    int bx = blockIdx.x;            // 16 * 8 * 16
    int b = bx >> 7;
    int r = bx & 127;
    int c0 = (r >> 4) * 64;
    int t0 = (r & 15) * 64;
    __shared__ half_t lds[64][72];
    int ci = threadIdx.x >> 4;          // 0..15
    int tj = (threadIdx.x & 15) * 4;
    for (int p = 0; p < 4; p++) {
        int c = c0 + ci + p * 16;
        float mean = stats[(b * 32 + (c >> 4)) * 2];
        float rsig = stats[(b * 32 + (c >> 4)) * 2 + 1];
        float sc = scale[c] * rsig;
        float bs = bias[c] - mean * sc;
        float4_t v = *(const float4_t*)(x + ((size_t)(b * 512 + c)) * 1024 + t0 + tj);
        half4_t hx;
        for (int j = 0; j < 4; j++) hx[j] = (half_t)(v[j] * sc + bs);
        *(half4_t*)(&lds[ci + p * 16][tj]) = hx;
    }
    __syncthreads();
    int cj = (threadIdx.x & 7) * 8;
    int ti = threadIdx.x >> 3;          // 0..31
    for (int p = 0; p < 2; p++) {
        int t = ti + p * 32;
        half8_t h;
        for (int j = 0; j < 8; j++) h[j] = lds[cj + j][t];
        *(half8_t*)(xnT + ((size_t)(b * 1024 + t0 + t)) * 512 + c0 + cj) = h;
    }
}

// ---------------- K3: QKV GEMM (M=16384 flat, BM=256, BN=128, K=512), 2-phase prefetch dbuf ----------
// o-tile in [0,512): Q -> qT[b][h][t][d];  [512,1024): K -> kT[b][h][t][d];  [1024,1536): V -> v[b][o][t]
__global__ __launch_bounds__(512) void k_qkv_gemm(const half_t* __restrict__ xnT,
                                                  const half_t* __restrict__ w16,
                                                  const float* __restrict__ qkv_b,
                                                  half_t* __restrict__ qT,
                                                  half_t* __restrict__ kT,
                                                  half_t* __restrict__ vg) {
    int bx = blockIdx.x;            // 64 * 12 = 768
    int mt = bx / 12;               // 0..63 -> flat rows mt*256
    int nt = bx % 12;
    int o0 = nt * 128;
    int b = mt >> 2;
    int t0 = (mt & 3) * 256;
    __shared__ half_t lA0[256 * 64], lA1[256 * 64];
    __shared__ half_t lB0[128 * 64], lB1[128 * 64];
    int tid = threadIdx.x;
    int lane = tid & 63, w = tid >> 6;       // 8 waves: 4(m) x 2(n)
    int wr = w >> 1, wc = w & 1;
    int l15 = lane & 15, l4 = lane >> 4;
    int srow = lane >> 3;                    // 0..7 within 8-row stripe
    int cs = (lane & 7) ^ srow;              // pre-swizzled global chunk
    const half_t* gA = xnT + (size_t)mt * 256 * 512;
    const half_t* gB = w16 + (size_t)o0 * 512;
    const bool qk = (o0 < 1024);
    f32x4 acc[4][4] = {};

    auto stage = [&](half_t* LA, half_t* LB, int kk) {
        #pragma unroll
        for (int p = 0; p < 4; p++) {        // A rows w*32 .. w*32+31
            int row = w * 32 + p * 8;
            gload16(gA + (size_t)(row + srow) * 512 + kk + cs * 8, &LA[row * 64]);
        }
        #pragma unroll
        for (int p = 0; p < 2; p++) {        // B rows w*16 .. w*16+15
            int row = w * 16 + p * 8;
            gload16(gB + (size_t)(row + srow) * 512 + kk + cs * 8, &LB[row * 64]);
        }
    };
    auto compute = [&](half_t* LA, half_t* LB) {
        #pragma unroll
        for (int ks = 0; ks < 2; ks++) {
            int colk = ks * 32 + l4 * 8;
            half8_t a[4], bb[4];
            #pragma unroll
            for (int mi = 0; mi < 4; mi++) a[mi]  = *(const half8_t*)swz(LA, wr * 64 + mi * 16 + l15, colk);
            #pragma unroll
            for (int ni = 0; ni < 4; ni++) bb[ni] = *(const half8_t*)swz(LB, wc * 64 + ni * 16 + l15, colk);
            __builtin_amdgcn_s_setprio(1);
            if (qk) {
                #pragma unroll
                for (int mi = 0; mi < 4; mi++)
                    #pragma unroll
                    for (int ni = 0; ni < 4; ni++)   // D[o][t]
                        acc[ni][mi] = __builtin_amdgcn_mfma_f32_16x16x32_f16(bb[ni], a[mi], acc[ni][mi], 0, 0, 0);
            } else {
                #pragma unroll
                for (int mi = 0; mi < 4; mi++)
                    #pragma unroll
                    for (int ni = 0; ni < 4; ni++)   // D[t][o]
                        acc[mi][ni] = __builtin_amdgcn_mfma_f32_16x16x32_f16(a[mi], bb[ni], acc[mi][ni], 0, 0, 0);
            }
            __builtin_amdgcn_s_setprio(0);
        }
    };

    stage(lA0, lB0, 0);
    asm volatile("s_waitcnt vmcnt(0)" ::: "memory");
    __syncthreads();
    #pragma unroll
    for (int kt = 0; kt < 4; kt++) {
        int kk = kt * 128;
        stage(lA1, lB1, kk + 64);
        compute(lA0, lB0);
        asm volatile("s_waitcnt vmcnt(0)" ::: "memory");
        __syncthreads();
        if (kt < 3) stage(lA0, lB0, kk + 128);
        compute(lA1, lB1);
        asm volatile("s_waitcnt vmcnt(0)" ::: "memory");
        __syncthreads();
    }

    if (qk) {
        // row = o = o0 + wc*64 + ni*16 + l4*4 + j ; col = t = t0 + wr*64 + mi*16 + l15
        half_t* dstbase = (o0 < 512) ? qT : kT;
        for (int ni = 0; ni < 4; ni++) {
            int obase = o0 + wc * 64 + ni * 16 + l4 * 4;
            int hh = (obase >> 6) & 7;
            int d0 = obase & 63;
            float4_t b4 = *(const float4_t*)(qkv_b + obase);
            half_t* dst = dstbase + ((size_t)(b * 8 + hh) * 1024) * 64 + d0;
            for (int mi = 0; mi < 4; mi++) {
                int t = t0 + wr * 64 + mi * 16 + l15;
                half4_t hv;
                for (int j = 0; j < 4; j++) hv[j] = (half_t)(acc[ni][mi][j] + b4[j]);
                *(half4_t*)(dst + (size_t)t * 64) = hv;
            }
        }
    } else {
        for (int ni = 0; ni < 4; ni++) {
            int oa = o0 + wc * 64 + ni * 16 + l15;       // absolute o
            float bias = qkv_b[oa];
            int ov = oa - 1024;
            for (int mi = 0; mi < 4; mi++) {
                int t = t0 + wr * 64 + mi * 16 + l4 * 4;
                half4_t hv;
                for (int j = 0; j < 4; j++) hv[j] = (half_t)(acc[mi][ni][j] + bias);
                *(half4_t*)(vg + ((size_t)(b * 512) + ov) * 1024 + t) = hv;
            }
        }
    }
}

// ---------------- K4: flash attention per (b,h,t-tile of 64) ----------------
// Q frags direct from global; K/V dbuf via gload_lds (static buffer names);
// row-sum l via ones-MFMA (reuses P B-frags); defer-max; max3-friendly reduce.
__global__ __launch_bounds__(256) void k_attn(const half_t* __restrict__ qT,
                                              const half_t* __restrict__ kT,
                                              const half_t* __restrict__ vg,
                                              half_t* __restrict__ aT) {
    int bx = blockIdx.x;            // 128 * 16
    int bh = bx >> 4;
    int t0 = (bx & 15) * 64;
    int b = bh >> 3, h = bh & 7;
    const half_t* kbase = kT + (size_t)bh * 1024 * 64;                // [s][d]
    const half_t* vbase = vg + ((size_t)(b * 512 + h * 64)) * 1024;  // [d][t]

    __shared__ half_t lK0[64 * 64], lK1[64 * 64];
    __shared__ half_t lV0[64 * 64], lV1[64 * 64];
    __shared__ half_t smp[4][16 * 64];   // per-wave P[t][s], swizzled

    int tid = threadIdx.x;
    int lane = tid & 63, w = tid >> 6;
    int l15 = lane & 15, l4 = lane >> 4;
    const float SC = 0.18033688f;        // 0.125 * log2(e)

    int srow = tid >> 3;                 // 0..31
    int cs = (tid & 7) ^ (srow & 7);     // pre-swizzled source chunk

    auto stage = [&](half_t* K, half_t* V, int s0) {
        #pragma unroll
        for (int rr = 0; rr < 2; rr++) {
            int row = rr * 32 + srow;
            gload16(kbase + (size_t)(s0 + row) * 64 + cs * 8, &K[(rr * 256 + w * 64) * 8]);
            gload16(vbase + (size_t)row * 1024 + s0 + cs * 8, &V[(rr * 256 + w * 64) * 8]);
        }
    };

    // Q B-frags direct from global (pre-scaled into exp2 domain)
    half8_t bq[2];
    {
        const half_t* qrow = qT + ((size_t)bh * 1024 + t0 + w * 16 + l15) * 64;
        for (int ks = 0; ks < 2; ks++) {
            half8_t raw = *(const half8_t*)(qrow + ks * 32 + l4 * 8);
            for (int j = 0; j < 8; j++) bq[ks][j] = (half_t)((float)raw[j] * SC);
        }
    }
    half8_t aone;
    #pragma unroll
    for (int j = 0; j < 8; j++) aone[j] = (half_t)1.0f;

    half_t* pw = smp[w];
    f32x4 oacc[4] = {};
    f32x4 lacc = {};
    float m_ = -1e30f;

    auto do_iter = [&](int it, half_t* Kc, half_t* Vc, half_t* Kn, half_t* Vn, bool pf) {
        if (pf) stage(Kn, Vn, (it + 1) * 64);
        // S^T tile (exp2 domain): st[ni][r] = S2[s-row][q-col=l15]
        f32x4 st[4] = {};
        __builtin_amdgcn_s_setprio(1);
        #pragma unroll
        for (int ks = 0; ks < 2; ks++) {
            int colk = ks * 32 + l4 * 8;
            #pragma unroll
            for (int ni = 0; ni < 4; ni++) {
                half8_t ak = *(const half8_t*)swz(Kc, ni * 16 + l15, colk);
                st[ni] = __builtin_amdgcn_mfma_f32_16x16x32_f16(ak, bq[ks], st[ni], 0, 0, 0);
            }
        }
        __builtin_amdgcn_s_setprio(0);
        // max over 16 lane-local s-values (max3-fusable triples) + 2 shfl
        float t0m = fmaxf(fmaxf(st[0][0], st[0][1]), st[0][2]);
        float t1m = fmaxf(fmaxf(st[0][3], st[1][0]), st[1][1]);
        float t2m = fmaxf(fmaxf(st[1][2], st[1][3]), st[2][0]);
        float t3m = fmaxf(fmaxf(st[2][1], st[2][2]), st[2][3]);
        float t4m = fmaxf(fmaxf(st[3][0], st[3][1]), st[3][2]);
        float tm  = fmaxf(fmaxf(fmaxf(t0m, t1m), fmaxf(t2m, t3m)), fmaxf(t4m, st[3][3]));
        tm = fmaxf(tm, __shfl_xor(tm, 16, 64));
        tm = fmaxf(tm, __shfl_xor(tm, 32, 64));
        // defer-max: rescale O,l only when running max grew by > 8 (P bounded by 2^8)
        if (__any(tm > m_ + 8.0f)) {
            float nm = fmaxf(m_, tm);
            float f = exp2f(m_ - nm);
            #pragma unroll
            for (int i = 0; i < 4; i++) lacc[i] *= f;
            #pragma unroll
            for (int mi = 0; mi < 4; mi++)
                for (int i = 0; i < 4; i++) oacc[mi][i] *= f;
            m_ = nm;
        }
        #pragma unroll
        for (int ni = 0; ni < 4; ni++) {
            float p0 = exp2f(st[ni][0] - m_), p1 = exp2f(st[ni][1] - m_);
            float p2 = exp2f(st[ni][2] - m_), p3 = exp2f(st[ni][3] - m_);
            half2_t lo = pk16(p0, p1);
            half2_t hi = pk16(p2, p3);
            half4_t ph = {lo[0], lo[1], hi[0], hi[1]};
            *(half4_t*)swz(pw, l15, ni * 16 + l4 * 4) = ph;   // P[t][s]
        }
        // O += V P^T ; l += 1 P^T  (A = V[d][s] / ones, B[k=s][col=t] = P rows)
        __builtin_amdgcn_s_setprio(1);
        #pragma unroll
        for (int ks = 0; ks < 2; ks++) {
            int colk = ks * 32 + l4 * 8;
            half8_t bp = *(const half8_t*)swz(pw, l15, colk);
            lacc = __builtin_amdgcn_mfma_f32_16x16x32_f16(aone, bp, lacc, 0, 0, 0);
            #pragma unroll
            for (int mi = 0; mi < 4; mi++) {
                half8_t av = *(const half8_t*)swz(Vc, mi * 16 + l15, colk);
                oacc[mi] = __builtin_amdgcn_mfma_f32_16x16x32_f16(av, bp, oacc[mi], 0, 0, 0);
            }
        }
        __builtin_amdgcn_s_setprio(0);
        asm volatile("s_waitcnt vmcnt(0)" ::: "memory");   // prefetch landed
        __syncthreads();                                   // publish; all waves done with cur
    };

    stage(lK0, lV0, 0);
    asm volatile("s_waitcnt vmcnt(0)" ::: "memory");
    __syncthreads();

    for (int hh = 0; hh < 8; hh++) {
        do_iter(2 * hh,     lK0, lV0, lK1, lV1, true);
        do_iter(2 * hh + 1, lK1, lV1, lK0, lV0, hh < 7);
    }

    // O /= l ; store aT[b][t][h*64+d]  (col t = l15 lane-local, rows d = mi*16+l4*4+i)
    float linv = 1.0f / lacc[0];
    int t = t0 + w * 16 + l15;
    for (int mi = 0; mi < 4; mi++) {
        half4_t hv;
        for (int i = 0; i < 4; i++) hv[i] = (half_t)(oacc[mi][i] * linv);
        *(half4_t*)(aT + ((size_t)(b * 1024) + t) * 512 + h * 64 + mi * 16 + l4 * 4) = hv;
    }
}

// ---------------- K5: proj GEMM + bias + residual (M=16384 flat, BM=256, BN=128), prefetch dbuf ------
__global__ __launch_bounds__(512) void k_proj_gemm(const half_t* __restrict__ aT,
                                                   const half_t* __restrict__ pw16,
                                                   const float* __restrict__ proj_b,
                                                   const float* __restrict__ x,
                                                   float* __restrict__ out) {
    int bx = blockIdx.x;            // 64 * 4 = 256
    int mt = bx / 4;
    int nt = bx % 4;
    int o0 = nt * 128;
    int b = mt >> 2;
    int t0 = (mt & 3) * 256;
    __shared__ half_t lA0[256 * 64], lA1[256 * 64];
    __shared__ half_t lB0[128 * 64], lB1[128 * 64];
    int tid = threadIdx.x;
    int lane = tid & 63, w = tid >> 6;
    int wr = w >> 1, wc = w & 1;
    int l15 = lane & 15, l4 = lane >> 4;
    int srow = lane >> 3;
    int cs = (lane & 7) ^ srow;
    const half_t* gA = aT + (size_t)mt * 256 * 512;
    const half_t* gB = pw16 + (size_t)o0 * 512;
    f32x4 acc[4][4] = {};

    auto stage = [&](half_t* LA, half_t* LB, int kk) {
        #pragma unroll
        for (int p = 0; p < 4; p++) {
            int row = w * 32 + p * 8;
            gload16(gA + (size_t)(row + srow) * 512 + kk + cs * 8, &LA[row * 64]);
        }
        #pragma unroll
        for (int p = 0; p < 2; p++) {
            int row = w * 16 + p * 8;
            gload16(gB + (size_t)(row + srow) * 512 + kk + cs * 8, &LB[row * 64]);
        }
    };
    auto compute = [&](half_t* LA, half_t* LB) {
        #pragma unroll
        for (int ks = 0; ks < 2; ks++) {
            int colk = ks * 32 + l4 * 8;
            half8_t a[4], bb[4];
            #pragma unroll
            for (int mi = 0; mi < 4; mi++) a[mi]  = *(const half8_t*)swz(LA, wr * 64 + mi * 16 + l15, colk);
            #pragma unroll
            for (int ni = 0; ni < 4; ni++) bb[ni] = *(const half8_t*)swz(LB, wc * 64 + ni * 16 + l15, colk);
            __builtin_amdgcn_s_setprio(1);
            #pragma unroll
            for (int mi = 0; mi < 4; mi++)
                #pragma unroll
                for (int ni = 0; ni < 4; ni++)
                    acc[mi][ni] = __builtin_amdgcn_mfma_f32_16x16x32_f16(a[mi], bb[ni], acc[mi][ni], 0, 0, 0);
            __builtin_amdgcn_s_setprio(0);
        }
    };

    stage(lA0, lB0, 0);
    asm volatile("s_waitcnt vmcnt(0)" ::: "memory");
    __syncthreads();
    #pragma unroll
    for (int kt = 0; kt < 4; kt++) {
        int kk = kt * 128;
        stage(lA1, lB1, kk + 64);
        compute(lA0, lB0);
        asm volatile("s_waitcnt vmcnt(0)" ::: "memory");
        __syncthreads();
        if (kt < 3) stage(lA0, lB0, kk + 128);
        compute(lA1, lB1);
        asm volatile("s_waitcnt vmcnt(0)" ::: "memory");
        __syncthreads();
    }

    for (int ni = 0; ni < 4; ni++) {
        int o = o0 + wc * 64 + ni * 16 + l15;
        float bias = proj_b[o];
        for (int mi = 0; mi < 4; mi++) {
            int t = t0 + wr * 64 + mi * 16 + l4 * 4;
            size_t idx = ((size_t)(b * 512) + o) * 1024 + t;
            float4_t xres = *(const float4_t*)(x + idx);
            float4_t ov;
            for (int j = 0; j < 4; j++) ov[j] = acc[mi][ni][j] + bias + xres[j];
            *(float4_t*)(out + idx) = ov;
        }
    }
}

extern "C" void kernel_launch(void* const* d_in, const int* in_sizes, int n_in,
                              void* d_out, int out_size, void* d_ws, size_t ws_size,
                              hipStream_t stream) {
    const float* x        = (const float*)d_in[0];
    const float* gn_scale = (const float*)d_in[1];
    const float* gn_bias  = (const float*)d_in[2];
    const float* qkv_w    = (const float*)d_in[3];
    const float* qkv_b    = (const float*)d_in[4];
    const float* proj_w   = (const float*)d_in[5];
    const float* proj_b   = (const float*)d_in[6];
    float* out = (float*)d_out;

    char* ws = (char*)d_ws;
    half_t* w16  = (half_t*)(ws + OFF_W16);
    half_t* pw16 = (half_t*)(ws + OFF_PW16);
    half_t* xnT  = (half_t*)(ws + OFF_XNT);
    half_t* qTp  = (half_t*)(ws + OFF_QT);
    half_t* kTp  = (half_t*)(ws + OFF_KT);
    half_t* vp   = (half_t*)(ws + OFF_V);
    half_t* aT   = (half_t*)(ws + OFF_AT);
    float*  stat = (float*) (ws + OFF_STAT);

    k_convert_w<<<1024, 256, 0, stream>>>(qkv_w, proj_w, w16, pw16);
    k_gn_stats<<<512, 256, 0, stream>>>(x, stat);
    k_gn_apply_t<<<2048, 256, 0, stream>>>(x, stat, gn_scale, gn_bias, xnT);
    k_qkv_gemm<<<768, 512, 0, stream>>>(xnT, w16, qkv_b, qTp, kTp, vp);
    k_attn<<<2048, 256, 0, stream>>>(qTp, kTp, vp, aT);
    k_proj_gemm<<<256, 512, 0, stream>>>(aT, pw16, proj_b, x, out);
}

// Round 8
// 239.826 us; speedup vs baseline: 1.2929x; 1.0476x over previous
//
#include <hip/hip_runtime.h>

typedef _Float16 half_t;
typedef __fp16 fp16x2_t __attribute__((ext_vector_type(2)));
typedef _Float16 half2_t __attribute__((ext_vector_type(2)));
typedef _Float16 half4_t __attribute__((ext_vector_type(4)));
typedef _Float16 half8_t __attribute__((ext_vector_type(8)));
typedef float f32x4 __attribute__((ext_vector_type(4)));
typedef float float4_t __attribute__((ext_vector_type(4)));

#define NB 16
#define NC 512
#define NT 1024
#define NHEAD 8
#define DH 64

// ---------------- workspace layout (bytes) ----------------
#define OFF_W16  ((size_t)0)                                  // qkv_w fp16 [1536][512]
#define OFF_PW16 (OFF_W16  + (size_t)1536*512*2)              // proj_w fp16 [512][512]
#define OFF_XNG  (OFF_PW16 + (size_t)512*512*2)               // xn  fp16 [16][32][1024][16] group-blocked
#define OFF_QT   (OFF_XNG  + (size_t)16*1024*512*2)           // qT  fp16 [16][8][1024][64]
#define OFF_KT   (OFF_QT   + (size_t)16*8*1024*64*2)          // kT  fp16 [16][8][1024][64]
#define OFF_V    (OFF_KT   + (size_t)16*8*1024*64*2)          // v   fp16 [16][512][1024]
#define OFF_AT   (OFF_V    + (size_t)16*512*1024*2)           // aT  fp16 [16][1024][512]

// async global->LDS, 16B per lane; LDS dest = wave-uniform base + lane*16
__device__ __forceinline__ void gload16(const half_t* g, half_t* l) {
    __builtin_amdgcn_global_load_lds(
        (const __attribute__((address_space(1))) void*)g,
        (__attribute__((address_space(3))) void*)l, 16, 0, 0);
}

// XOR-swizzled LDS address for tiles with 128B row stride:
// byte = (row*128 + col*2) ^ ((row&7)<<4); 16B-chunk-preserving, bijective.
__device__ __forceinline__ half_t* swz(half_t* base, int row, int col) {
    int byte = ((row << 7) + (col << 1)) ^ ((row & 7) << 4);
    return (half_t*)((char*)base + byte);
}

// packed f32x2 -> f16x2 (rtz)
__device__ __forceinline__ half2_t pk16(float a, float b) {
    fp16x2_t r = __builtin_amdgcn_cvt_pkrtz(a, b);
    return __builtin_bit_cast(half2_t, r);
}

// ---------------- K0: weights fp32 -> fp16 ----------------
__global__ void k_convert_w(const float* __restrict__ qkv_w, const float* __restrict__ proj_w,
                            half_t* __restrict__ w16, half_t* __restrict__ pw16) {
    int i = (blockIdx.x * 256 + threadIdx.x) * 4;
    const int NQ = 1536 * 512;
    if (i < NQ) {
        float4_t v = *(const float4_t*)(qkv_w + i);
        half4_t h; for (int j = 0; j < 4; j++) h[j] = (half_t)v[j];
        *(half4_t*)(w16 + i) = h;
    } else {
        int k = i - NQ;
        float4_t v = *(const float4_t*)(proj_w + k);
        half4_t h; for (int j = 0; j < 4; j++) h[j] = (half_t)v[j];
        *(half4_t*)(pw16 + k) = h;
    }
}

// ---------------- K1: fused GroupNorm (stats + apply), x read ONCE ----------------
// one block per (b,g); x slice [16c][1024t] cached in LDS; output group-blocked
// xn[b][g][t][16c] -> coalesced 2KB/wave stores.
__global__ __launch_bounds__(256) void k_gn_fused(const float* __restrict__ x,
                                                  const float* __restrict__ scale,
                                                  const float* __restrict__ bias,
                                                  half_t* __restrict__ xnG) {
    int bg = blockIdx.x;              // b*32 + g
    int g = bg & 31;
    __shared__ float xl[16][1024];
    __shared__ float red[2][4];
    __shared__ float scb[2][16];
    const float* xs = x + (size_t)bg * 16384;
    int tid = threadIdx.x;
    float s = 0.f, sq = 0.f;
    #pragma unroll
    for (int r = 0; r < 16; r++) {
        float4_t v = *(const float4_t*)(xs + r * 1024 + tid * 4);
        *(float4_t*)(&xl[r][tid * 4]) = v;
        for (int j = 0; j < 4; j++) { s += v[j]; sq += v[j] * v[j]; }
    }
    for (int m = 1; m < 64; m <<= 1) { s += __shfl_xor(s, m, 64); sq += __shfl_xor(sq, m, 64); }
    int wid = tid >> 6;
    if ((tid & 63) == 0) { red[0][wid] = s; red[1][wid] = sq; }
    __syncthreads();
    s  = red[0][0] + red[0][1] + red[0][2] + red[0][3];
    sq = red[1][0] + red[1][1] + red[1][2] + red[1][3];
    float mean = s * (1.f / 16384.f);
    float rsig = rsqrtf(sq * (1.f / 16384.f) - mean * mean + 1e-5f);
    if (tid < 16) {
        float sc = scale[g * 16 + tid] * rsig;
        scb[0][tid] = sc;
        scb[1][tid] = bias[g * 16 + tid] - mean * sc;
    }
    __syncthreads();
    half_t* dst = xnG + (size_t)bg * 1024 * 16;
    #pragma unroll
    for (int k = 0; k < 4; k++) {
        int t = k * 256 + tid;
        half8_t h0, h1;
        #pragma unroll
        for (int c = 0; c < 8; c++) h0[c] = (half_t)(xl[c][t] * scb[0][c] + scb[1][c]);
        #pragma unroll
        for (int c = 0; c < 8; c++) h1[c] = (half_t)(xl[c + 8][t] * scb[0][c + 8] + scb[1][c + 8]);
        *(half8_t*)(dst + (size_t)t * 16)     = h0;
        *(half8_t*)(dst + (size_t)t * 16 + 8) = h1;
    }
}

// ---------------- K3: QKV GEMM (M=16384 flat, BM=256, BN=128, K=512), prefetch dbuf, XCD-swizzled ----
// o-tile in [0,512): Q -> qT[b][h][t][d];  [512,1024): K -> kT[b][h][t][d];  [1024,1536): V -> v[b][o][t]
__global__ __launch_bounds__(512) void k_qkv_gemm(const half_t* __restrict__ xnG,
                                                  const half_t* __restrict__ w16,
                                                  const float* __restrict__ qkv_b,
                                                  half_t* __restrict__ qT,
                                                  half_t* __restrict__ kT,
                                                  half_t* __restrict__ vg) {
    int bx = blockIdx.x;            // 768 = 64 mt * 12 nt
    // T1: all 12 nt of one mt on the same XCD (A-tile L2-resident)
    int xcd = bx & 7, sfl = bx >> 3;           // sfl 0..95
    int mt = xcd + ((sfl / 12) << 3);          // 0..63
    int nt = sfl % 12;
    int o0 = nt * 128;
    int b = mt >> 2;
    int t0 = (mt & 3) * 256;
    __shared__ half_t lA0[256 * 64], lA1[256 * 64];
    __shared__ half_t lB0[128 * 64], lB1[128 * 64];
    int tid = threadIdx.x;
    int lane = tid & 63, w = tid >> 6;       // 8 waves: 4(m) x 2(n)
    int wr = w >> 1, wc = w & 1;
    int l15 = lane & 15, l4 = lane >> 4;
    int srow = lane >> 3;                    // 0..7 within 8-row stripe
    int cs = (lane & 7) ^ srow;              // pre-swizzled global chunk
    int cshi = cs >> 1, csoff = (cs & 1) * 8;
    const half_t* gAb = xnG + (size_t)(b * 32) * 1024 * 16;   // group-blocked A
    const half_t* gB = w16 + (size_t)o0 * 512;
    const bool qk = (o0 < 1024);
    f32x4 acc[4][4] = {};

    auto stage = [&](half_t* LA, half_t* LB, int kk) {
        // A chunk c = kk + cs*8 lives at group g = kk/16 + cs/2, offset (cs&1)*8
        const half_t* ga = gAb + ((size_t)(((kk >> 4) + cshi) * 1024) + t0) * 16 + csoff;
        #pragma unroll
        for (int p = 0; p < 4; p++) {        // A rows w*32 .. w*32+31
            int row = w * 32 + p * 8;
            gload16(ga + (size_t)(row + srow) * 16, &LA[row * 64]);
        }
        #pragma unroll
        for (int p = 0; p < 2; p++) {        // B rows w*16 .. w*16+15
            int row = w * 16 + p * 8;
            gload16(gB + (size_t)(row + srow) * 512 + kk + cs * 8, &LB[row * 64]);
        }
    };
    auto compute = [&](half_t* LA, half_t* LB) {
        #pragma unroll
        for (int ks = 0; ks < 2; ks++) {
            int colk = ks * 32 + l4 * 8;
            half8_t a[4], bb[4];
            #pragma unroll
            for (int mi = 0; mi < 4; mi++) a[mi]  = *(const half8_t*)swz(LA, wr * 64 + mi * 16 + l15, colk);
            #pragma unroll
            for (int ni = 0; ni < 4; ni++) bb[ni] = *(const half8_t*)swz(LB, wc * 64 + ni * 16 + l15, colk);
            __builtin_amdgcn_s_setprio(1);
            if (qk) {
                #pragma unroll
                for (int mi = 0; mi < 4; mi++)
                    #pragma unroll
                    for (int ni = 0; ni < 4; ni++)   // D[o][t]
                        acc[ni][mi] = __builtin_amdgcn_mfma_f32_16x16x32_f16(bb[ni], a[mi], acc[ni][mi], 0, 0, 0);
            } else {
                #pragma unroll
                for (int mi = 0; mi < 4; mi++)
                    #pragma unroll
                    for (int ni = 0; ni < 4; ni++)   // D[t][o]
                        acc[mi][ni] = __builtin_amdgcn_mfma_f32_16x16x32_f16(a[mi], bb[ni], acc[mi][ni], 0, 0, 0);
            }
            __builtin_amdgcn_s_setprio(0);
        }
    };

    stage(lA0, lB0, 0);
    asm volatile("s_waitcnt vmcnt(0)" ::: "memory");
    __syncthreads();
    #pragma unroll
    for (int kt = 0; kt < 4; kt++) {
        int kk = kt * 128;
        stage(lA1, lB1, kk + 64);
        compute(lA0, lB0);
        asm volatile("s_waitcnt vmcnt(0)" ::: "memory");
        __syncthreads();
        if (kt < 3) stage(lA0, lB0, kk + 128);
        compute(lA1, lB1);
        asm volatile("s_waitcnt vmcnt(0)" ::: "memory");
        __syncthreads();
    }

    if (qk) {
        // row = o = o0 + wc*64 + ni*16 + l4*4 + j ; col = t = t0 + wr*64 + mi*16 + l15
        half_t* dstbase = (o0 < 512) ? qT : kT;
        for (int ni = 0; ni < 4; ni++) {
            int obase = o0 + wc * 64 + ni * 16 + l4 * 4;
            int hh = (obase >> 6) & 7;
            int d0 = obase & 63;
            float4_t b4 = *(const float4_t*)(qkv_b + obase);
            half_t* dst = dstbase + ((size_t)(b * 8 + hh) * 1024) * 64 + d0;
            for (int mi = 0; mi < 4; mi++) {
                int t = t0 + wr * 64 + mi * 16 + l15;
                half4_t hv;
                for (int j = 0; j < 4; j++) hv[j] = (half_t)(acc[ni][mi][j] + b4[j]);
                *(half4_t*)(dst + (size_t)t * 64) = hv;
            }
        }
    } else {
        for (int ni = 0; ni < 4; ni++) {
            int oa = o0 + wc * 64 + ni * 16 + l15;       // absolute o
            float bias = qkv_b[oa];
            int ov = oa - 1024;
            for (int mi = 0; mi < 4; mi++) {
                int t = t0 + wr * 64 + mi * 16 + l4 * 4;
                half4_t hv;
                for (int j = 0; j < 4; j++) hv[j] = (half_t)(acc[mi][ni][j] + bias);
                *(half4_t*)(vg + ((size_t)(b * 512) + ov) * 1024 + t) = hv;
            }
        }
    }
}

// ---------------- K4: flash attention per (b,h,t-tile of 64), XCD-swizzled ----------------
// Q frags direct from global; K/V dbuf via gload_lds (static buffers);
// bias-init QK^T accumulators with -m_ (kills per-element subtract); ones-MFMA row-sum.
__global__ __launch_bounds__(256) void k_attn(const half_t* __restrict__ qT,
                                              const half_t* __restrict__ kT,
                                              const half_t* __restrict__ vg,
                                              half_t* __restrict__ aT) {
    int bx = blockIdx.x;            // 2048
    // T1: all 16 t-tiles of one (b,h) on the same XCD (K/V L2-resident)
    int xcd = bx & 7, sfl = bx >> 3;          // sfl 0..255
    int bh = xcd + ((sfl >> 4) << 3);         // 0..127
    int t0 = (sfl & 15) * 64;
    int b = bh >> 3, h = bh & 7;
    const half_t* kbase = kT + (size_t)bh * 1024 * 64;                // [s][d]
    const half_t* vbase = vg + ((size_t)(b * 512 + h * 64)) * 1024;  // [d][t]

    __shared__ half_t lK0[64 * 64], lK1[64 * 64];
    __shared__ half_t lV0[64 * 64], lV1[64 * 64];
    __shared__ half_t smp[4][16 * 64];   // per-wave P[t][s], swizzled

    int tid = threadIdx.x;
    int lane = tid & 63, w = tid >> 6;
    int l15 = lane & 15, l4 = lane >> 4;
    const float SC = 0.18033688f;        // 0.125 * log2(e)

    int srow = tid >> 3;                 // 0..31
    int cs = (tid & 7) ^ (srow & 7);     // pre-swizzled source chunk

    auto stage = [&](half_t* K, half_t* V, int s0) {
        #pragma unroll
        for (int rr = 0; rr < 2; rr++) {
            int row = rr * 32 + srow;
            gload16(kbase + (size_t)(s0 + row) * 64 + cs * 8, &K[(rr * 256 + w * 64) * 8]);
            gload16(vbase + (size_t)row * 1024 + s0 + cs * 8, &V[(rr * 256 + w * 64) * 8]);
        }
    };

    // Q B-frags direct from global (pre-scaled into exp2 domain)
    half8_t bq[2];
    {
        const half_t* qrow = qT + ((size_t)bh * 1024 + t0 + w * 16 + l15) * 64;
        for (int ks = 0; ks < 2; ks++) {
            half8_t raw = *(const half8_t*)(qrow + ks * 32 + l4 * 8);
            for (int j = 0; j < 8; j++) bq[ks][j] = (half_t)((float)raw[j] * SC);
        }
    }
    half8_t aone;
    #pragma unroll
    for (int j = 0; j < 8; j++) aone[j] = (half_t)1.0f;

    half_t* pw = smp[w];
    f32x4 oacc[4] = {};
    f32x4 lacc = {};
    float m_ = 0.f;                      // running max (exp2 domain), biased into MFMA C-init

    auto do_iter = [&](int it, half_t* Kc, half_t* Vc, half_t* Kn, half_t* Vn, bool pf) {
        if (pf) stage(Kn, Vn, (it + 1) * 64);
        // S^T tile biased by -m_: st = S2 - m_  (C-init = -m_)
        f32x4 st[4];
        #pragma unroll
        for (int ni = 0; ni < 4; ni++)
            for (int rr = 0; rr < 4; rr++) st[ni][rr] = -m_;
        __builtin_amdgcn_s_setprio(1);
        #pragma unroll
        for (int ks = 0; ks < 2; ks++) {
            int colk = ks * 32 + l4 * 8;
            #pragma unroll
            for (int ni = 0; ni < 4; ni++) {
                half8_t ak = *(const half8_t*)swz(Kc, ni * 16 + l15, colk);
                st[ni] = __builtin_amdgcn_mfma_f32_16x16x32_f16(ak, bq[ks], st[ni], 0, 0, 0);
            }
        }
        __builtin_amdgcn_s_setprio(0);
        // biased tile max per q-column + 2-step cross-group reduce
        float t0m = fmaxf(fmaxf(st[0][0], st[0][1]), st[0][2]);
        float t1m = fmaxf(fmaxf(st[0][3], st[1][0]), st[1][1]);
        float t2m = fmaxf(fmaxf(st[1][2], st[1][3]), st[2][0]);
        float t3m = fmaxf(fmaxf(st[2][1], st[2][2]), st[2][3]);
        float t4m = fmaxf(fmaxf(st[3][0], st[3][1]), st[3][2]);
        float tm  = fmaxf(fmaxf(fmaxf(t0m, t1m), fmaxf(t2m, t3m)), fmaxf(t4m, st[3][3]));
        tm = fmaxf(tm, __shfl_xor(tm, 16, 64));
        tm = fmaxf(tm, __shfl_xor(tm, 32, 64));
        // defer-max: rescale only when biased max grew past THR=8 (P bounded by 2^8)
        if (__any(tm > 8.0f)) {
            float d = fmaxf(tm, 0.f);
            float f = exp2f(-d);
            #pragma unroll
            for (int i = 0; i < 4; i++) lacc[i] *= f;
            #pragma unroll
            for (int mi = 0; mi < 4; mi++)
                for (int i = 0; i < 4; i++) oacc[mi][i] *= f;
            #pragma unroll
            for (int ni = 0; ni < 4; ni++)
                for (int rr = 0; rr < 4; rr++) st[ni][rr] -= d;
            m_ += d;
        }
        #pragma unroll
        for (int ni = 0; ni < 4; ni++) {
            float p0 = exp2f(st[ni][0]), p1 = exp2f(st[ni][1]);
            float p2 = exp2f(st[ni][2]), p3 = exp2f(st[ni][3]);
            half2_t lo = pk16(p0, p1);
            half2_t hi = pk16(p2, p3);
            half4_t ph = {lo[0], lo[1], hi[0], hi[1]};
            *(half4_t*)swz(pw, l15, ni * 16 + l4 * 4) = ph;   // P[t][s]
        }
        // O += V P^T ; l += 1 P^T  (A = V[d][s] / ones, B[k=s][col=t] = P rows)
        __builtin_amdgcn_s_setprio(1);
        #pragma unroll
        for (int ks = 0; ks < 2; ks++) {
            int colk = ks * 32 + l4 * 8;
            half8_t bp = *(const half8_t*)swz(pw, l15, colk);
            lacc = __builtin_amdgcn_mfma_f32_16x16x32_f16(aone, bp, lacc, 0, 0, 0);
            #pragma unroll
            for (int mi = 0; mi < 4; mi++) {
                half8_t av = *(const half8_t*)swz(Vc, mi * 16 + l15, colk);
                oacc[mi] = __builtin_amdgcn_mfma_f32_16x16x32_f16(av, bp, oacc[mi], 0, 0, 0);
            }
        }
        __builtin_amdgcn_s_setprio(0);
        asm volatile("s_waitcnt vmcnt(0)" ::: "memory");   // prefetch landed
        __syncthreads();                                   // publish; all waves done with cur
    };

    stage(lK0, lV0, 0);
    asm volatile("s_waitcnt vmcnt(0)" ::: "memory");
    __syncthreads();

    for (int hh = 0; hh < 8; hh++) {
        do_iter(2 * hh,     lK0, lV0, lK1, lV1, true);
        do_iter(2 * hh + 1, lK1, lV1, lK0, lV0, hh < 7);
    }

    // O /= l ; store aT[b][t][h*64+d]  (col t = l15 lane-local, rows d = mi*16+l4*4+i)
    float linv = 1.0f / lacc[0];
    int t = t0 + w * 16 + l15;
    for (int mi = 0; mi < 4; mi++) {
        half4_t hv;
        for (int i = 0; i < 4; i++) hv[i] = (half_t)(oacc[mi][i] * linv);
        *(half4_t*)(aT + ((size_t)(b * 1024) + t) * 512 + h * 64 + mi * 16 + l4 * 4) = hv;
    }
}

// ---------------- K5: proj GEMM + bias + residual (M=16384 flat, BM=256, BN=128), XCD-swizzled ------
__global__ __launch_bounds__(512) void k_proj_gemm(const half_t* __restrict__ aT,
                                                   const half_t* __restrict__ pw16,
                                                   const float* __restrict__ proj_b,
                                                   const float* __restrict__ x,
                                                   float* __restrict__ out) {
    int bx = blockIdx.x;            // 256 = 64 mt * 4 nt
    int xcd = bx & 7, sfl = bx >> 3;           // 0..31
    int mt = xcd + ((sfl >> 2) << 3);
    int nt = sfl & 3;
    int o0 = nt * 128;
    int b = mt >> 2;
    int t0 = (mt & 3) * 256;
    __shared__ half_t lA0[256 * 64], lA1[256 * 64];
    __shared__ half_t lB0[128 * 64], lB1[128 * 64];
    int tid = threadIdx.x;
    int lane = tid & 63, w = tid >> 6;
    int wr = w >> 1, wc = w & 1;
    int l15 = lane & 15, l4 = lane >> 4;
    int srow = lane >> 3;
    int cs = (lane & 7) ^ srow;
    const half_t* gA = aT + (size_t)mt * 256 * 512;
    const half_t* gB = pw16 + (size_t)o0 * 512;
    f32x4 acc[4][4] = {};

    auto stage = [&](half_t* LA, half_t* LB, int kk) {
        #pragma unroll
        for (int p = 0; p < 4; p++) {
            int row = w * 32 + p * 8;
            gload16(gA + (size_t)(row + srow) * 512 + kk + cs * 8, &LA[row * 64]);
        }
        #pragma unroll
        for (int p = 0; p < 2; p++) {
            int row = w * 16 + p * 8;
            gload16(gB + (size_t)(row + srow) * 512 + kk + cs * 8, &LB[row * 64]);
        }
    };
    auto compute = [&](half_t* LA, half_t* LB) {
        #pragma unroll
        for (int ks = 0; ks < 2; ks++) {
            int colk = ks * 32 + l4 * 8;
            half8_t a[4], bb[4];
            #pragma unroll
            for (int mi = 0; mi < 4; mi++) a[mi]  = *(const half8_t*)swz(LA, wr * 64 + mi * 16 + l15, colk);
            #pragma unroll
            for (int ni = 0; ni < 4; ni++) bb[ni] = *(const half8_t*)swz(LB, wc * 64 + ni * 16 + l15, colk);
            __builtin_amdgcn_s_setprio(1);
            #pragma unroll
            for (int mi = 0; mi < 4; mi++)
                #pragma unroll
                for (int ni = 0; ni < 4; ni++)
                    acc[mi][ni] = __builtin_amdgcn_mfma_f32_16x16x32_f16(a[mi], bb[ni], acc[mi][ni], 0, 0, 0);
            __builtin_amdgcn_s_setprio(0);
        }
    };

    stage(lA0, lB0, 0);
    asm volatile("s_waitcnt vmcnt(0)" ::: "memory");
    __syncthreads();
    #pragma unroll
    for (int kt = 0; kt < 4; kt++) {
        int kk = kt * 128;
        stage(lA1, lB1, kk + 64);
        compute(lA0, lB0);
        asm volatile("s_waitcnt vmcnt(0)" ::: "memory");
        __syncthreads();
        if (kt < 3) stage(lA0, lB0, kk + 128);
        compute(lA1, lB1);
        asm volatile("s_waitcnt vmcnt(0)" ::: "memory");
        __syncthreads();
    }

    for (int ni = 0; ni < 4; ni++) {
        int o = o0 + wc * 64 + ni * 16 + l15;
        float bias = proj_b[o];
        for (int mi = 0; mi < 4; mi++) {
            int t = t0 + wr * 64 + mi * 16 + l4 * 4;
            size_t idx = ((size_t)(b * 512) + o) * 1024 + t;
            float4_t xres = *(const float4_t*)(x + idx);
            float4_t ov;
            for (int j = 0; j < 4; j++) ov[j] = acc[mi][ni][j] + bias + xres[j];
            *(float4_t*)(out + idx) = ov;
        }
    }
}

extern "C" void kernel_launch(void* const* d_in, const int* in_sizes, int n_in,
                              void* d_out, int out_size, void* d_ws, size_t ws_size,
                              hipStream_t stream) {
    const float* x        = (const float*)d_in[0];
    const float* gn_scale = (const float*)d_in[1];
    const float* gn_bias  = (const float*)d_in[2];
    const float* qkv_w    = (const float*)d_in[3];
    const float* qkv_b    = (const float*)d_in[4];
    const float* proj_w   = (const float*)d_in[5];
    const float* proj_b   = (const float*)d_in[6];
    float* out = (float*)d_out;

    char* ws = (char*)d_ws;
    half_t* w16  = (half_t*)(ws + OFF_W16);
    half_t* pw16 = (half_t*)(ws + OFF_PW16);
    half_t* xnG  = (half_t*)(ws + OFF_XNG);
    half_t* qTp  = (half_t*)(ws + OFF_QT);
    half_t* kTp  = (half_t*)(ws + OFF_KT);
    half_t* vp   = (half_t*)(ws + OFF_V);
    half_t* aT   = (half_t*)(ws + OFF_AT);

    k_convert_w<<<1024, 256, 0, stream>>>(qkv_w, proj_w, w16, pw16);
    k_gn_fused<<<512, 256, 0, stream>>>(x, gn_scale, gn_bias, xnG);
    k_qkv_gemm<<<768, 512, 0, stream>>>(xnG, w16, qkv_b, qTp, kTp, vp);
    k_attn<<<2048, 256, 0, stream>>>(qTp, kTp, vp, aT);
    k_proj_gemm<<<256, 512, 0, stream>>>(aT, pw16, proj_b, x, out);
}

// Round 9
// 232.443 us; speedup vs baseline: 1.3339x; 1.0318x over previous
//
#include <hip/hip_runtime.h>

typedef _Float16 half_t;
typedef __fp16 fp16x2_t __attribute__((ext_vector_type(2)));
typedef _Float16 half2_t __attribute__((ext_vector_type(2)));
typedef _Float16 half4_t __attribute__((ext_vector_type(4)));
typedef _Float16 half8_t __attribute__((ext_vector_type(8)));
typedef float f32x4 __attribute__((ext_vector_type(4)));
typedef float float4_t __attribute__((ext_vector_type(4)));

#define NB 16
#define NC 512
#define NT 1024
#define NHEAD 8
#define DH 64

// ---------------- workspace layout (bytes) ----------------
#define OFF_W16  ((size_t)0)                                  // qkv_w fp16 [1536][512]
#define OFF_PW16 (OFF_W16  + (size_t)1536*512*2)              // proj_w fp16 [512][512]
#define OFF_XNG  (OFF_PW16 + (size_t)512*512*2)               // xn  fp16 [16][32][1024][16] group-blocked
#define OFF_QT   (OFF_XNG  + (size_t)16*1024*512*2)           // qT  fp16 [16][8][1024][64]
#define OFF_KT   (OFF_QT   + (size_t)16*8*1024*64*2)          // kT  fp16 [16][8][1024][64]
#define OFF_V    (OFF_KT   + (size_t)16*8*1024*64*2)          // v   fp16 [16][512][1024]
#define OFF_AT   (OFF_V    + (size_t)16*512*1024*2)           // aT  fp16 [16][1024][512]

// async global->LDS, 16B per lane; LDS dest = wave-uniform base + lane*16
__device__ __forceinline__ void gload16(const half_t* g, half_t* l) {
    __builtin_amdgcn_global_load_lds(
        (const __attribute__((address_space(1))) void*)g,
        (__attribute__((address_space(3))) void*)l, 16, 0, 0);
}

// XOR-swizzled LDS address for tiles with 128B row stride:
// byte = (row*128 + col*2) ^ ((row&7)<<4); 16B-chunk-preserving, bijective.
__device__ __forceinline__ half_t* swz(half_t* base, int row, int col) {
    int byte = ((row << 7) + (col << 1)) ^ ((row & 7) << 4);
    return (half_t*)((char*)base + byte);
}

// packed f32x2 -> f16x2 (rtz)
__device__ __forceinline__ half2_t pk16(float a, float b) {
    fp16x2_t r = __builtin_amdgcn_cvt_pkrtz(a, b);
    return __builtin_bit_cast(half2_t, r);
}

// ---------------- K0: weights fp32 -> fp16 ----------------
__global__ void k_convert_w(const float* __restrict__ qkv_w, const float* __restrict__ proj_w,
                            half_t* __restrict__ w16, half_t* __restrict__ pw16) {
    int i = (blockIdx.x * 256 + threadIdx.x) * 4;
    const int NQ = 1536 * 512;
    if (i < NQ) {
        float4_t v = *(const float4_t*)(qkv_w + i);
        half4_t h; for (int j = 0; j < 4; j++) h[j] = (half_t)v[j];
        *(half4_t*)(w16 + i) = h;
    } else {
        int k = i - NQ;
        float4_t v = *(const float4_t*)(proj_w + k);
        half4_t h; for (int j = 0; j < 4; j++) h[j] = (half_t)v[j];
        *(half4_t*)(pw16 + k) = h;
    }
}

// ---------------- K1: fused GroupNorm (stats + apply), x read ONCE ----------------
__global__ __launch_bounds__(256) void k_gn_fused(const float* __restrict__ x,
                                                  const float* __restrict__ scale,
                                                  const float* __restrict__ bias,
                                                  half_t* __restrict__ xnG) {
    int bg = blockIdx.x;              // b*32 + g
    int g = bg & 31;
    __shared__ float xl[16][1024];
    __shared__ float red[2][4];
    __shared__ float scb[2][16];
    const float* xs = x + (size_t)bg * 16384;
    int tid = threadIdx.x;
    float s = 0.f, sq = 0.f;
    #pragma unroll
    for (int r = 0; r < 16; r++) {
        float4_t v = *(const float4_t*)(xs + r * 1024 + tid * 4);
        *(float4_t*)(&xl[r][tid * 4]) = v;
        for (int j = 0; j < 4; j++) { s += v[j]; sq += v[j] * v[j]; }
    }
    for (int m = 1; m < 64; m <<= 1) { s += __shfl_xor(s, m, 64); sq += __shfl_xor(sq, m, 64); }
    int wid = tid >> 6;
    if ((tid & 63) == 0) { red[0][wid] = s; red[1][wid] = sq; }
    __syncthreads();
    s  = red[0][0] + red[0][1] + red[0][2] + red[0][3];
    sq = red[1][0] + red[1][1] + red[1][2] + red[1][3];
    float mean = s * (1.f / 16384.f);
    float rsig = rsqrtf(sq * (1.f / 16384.f) - mean * mean + 1e-5f);
    if (tid < 16) {
        float sc = scale[g * 16 + tid] * rsig;
        scb[0][tid] = sc;
        scb[1][tid] = bias[g * 16 + tid] - mean * sc;
    }
    __syncthreads();
    half_t* dst = xnG + (size_t)bg * 1024 * 16;
    #pragma unroll
    for (int k = 0; k < 4; k++) {
        int t = k * 256 + tid;
        half8_t h0, h1;
        #pragma unroll
        for (int c = 0; c < 8; c++) h0[c] = (half_t)(xl[c][t] * scb[0][c] + scb[1][c]);
        #pragma unroll
        for (int c = 0; c < 8; c++) h1[c] = (half_t)(xl[c + 8][t] * scb[0][c + 8] + scb[1][c + 8]);
        *(half8_t*)(dst + (size_t)t * 16)     = h0;
        *(half8_t*)(dst + (size_t)t * 16 + 8) = h1;
    }
}

// ---------------- K3: QKV GEMM (M=16384 flat, BM=256, BN=128, K=512), prefetch dbuf, XCD-swizzled ----
// o-tile in [0,512): Q -> qT[b][h][t][d];  [512,1024): K -> kT[b][h][t][d];  [1024,1536): V -> v[b][o][t]
__global__ __launch_bounds__(512) void k_qkv_gemm(const half_t* __restrict__ xnG,
                                                  const half_t* __restrict__ w16,
                                                  const float* __restrict__ qkv_b,
                                                  half_t* __restrict__ qT,
                                                  half_t* __restrict__ kT,
                                                  half_t* __restrict__ vg) {
    int bx = blockIdx.x;            // 768 = 64 mt * 12 nt
    // T1: all 12 nt of one mt on the same XCD (A-tile L2-resident)
    int xcd = bx & 7, sfl = bx >> 3;           // sfl 0..95
    int mt = xcd + ((sfl / 12) << 3);          // 0..63
    int nt = sfl % 12;
    int o0 = nt * 128;
    int b = mt >> 2;
    int t0 = (mt & 3) * 256;
    __shared__ half_t lA0[256 * 64], lA1[256 * 64];
    __shared__ half_t lB0[128 * 64], lB1[128 * 64];
    int tid = threadIdx.x;
    int lane = tid & 63, w = tid >> 6;       // 8 waves: 4(m) x 2(n)
    int wr = w >> 1, wc = w & 1;
    int l15 = lane & 15, l4 = lane >> 4;
    int srow = lane >> 3;                    // 0..7 within 8-row stripe
    int cs = (lane & 7) ^ srow;              // pre-swizzled global chunk
    int cshi = cs >> 1, csoff = (cs & 1) * 8;
    const half_t* gAb = xnG + (size_t)(b * 32) * 1024 * 16;   // group-blocked A
    const half_t* gB = w16 + (size_t)o0 * 512;
    const bool qk = (o0 < 1024);
    f32x4 acc[4][4] = {};

    auto stage = [&](half_t* LA, half_t* LB, int kk) {
        // A chunk c = kk + cs*8 lives at group g = kk/16 + cs/2, offset (cs&1)*8
        const half_t* ga = gAb + ((size_t)(((kk >> 4) + cshi) * 1024) + t0) * 16 + csoff;
        #pragma unroll
        for (int p = 0; p < 4; p++) {        // A rows w*32 .. w*32+31
            int row = w * 32 + p * 8;
            gload16(ga + (size_t)(row + srow) * 16, &LA[row * 64]);
        }
        #pragma unroll
        for (int p = 0; p < 2; p++) {        // B rows w*16 .. w*16+15
            int row = w * 16 + p * 8;
            gload16(gB + (size_t)(row + srow) * 512 + kk + cs * 8, &LB[row * 64]);
        }
    };
    auto compute = [&](half_t* LA, half_t* LB) {
        #pragma unroll
        for (int ks = 0; ks < 2; ks++) {
            int colk = ks * 32 + l4 * 8;
            half8_t a[4], bb[4];
            #pragma unroll
            for (int mi = 0; mi < 4; mi++) a[mi]  = *(const half8_t*)swz(LA, wr * 64 + mi * 16 + l15, colk);
            #pragma unroll
            for (int ni = 0; ni < 4; ni++) bb[ni] = *(const half8_t*)swz(LB, wc * 64 + ni * 16 + l15, colk);
            __builtin_amdgcn_s_setprio(1);
            if (qk) {
                #pragma unroll
                for (int mi = 0; mi < 4; mi++)
                    #pragma unroll
                    for (int ni = 0; ni < 4; ni++)   // D[o][t]
                        acc[ni][mi] = __builtin_amdgcn_mfma_f32_16x16x32_f16(bb[ni], a[mi], acc[ni][mi], 0, 0, 0);
            } else {
                #pragma unroll
                for (int mi = 0; mi < 4; mi++)
                    #pragma unroll
                    for (int ni = 0; ni < 4; ni++)   // D[t][o]
                        acc[mi][ni] = __builtin_amdgcn_mfma_f32_16x16x32_f16(a[mi], bb[ni], acc[mi][ni], 0, 0, 0);
            }
            __builtin_amdgcn_s_setprio(0);
        }
    };

    stage(lA0, lB0, 0);
    asm volatile("s_waitcnt vmcnt(0)" ::: "memory");
    __syncthreads();
    #pragma unroll
    for (int kt = 0; kt < 4; kt++) {
        int kk = kt * 128;
        stage(lA1, lB1, kk + 64);
        compute(lA0, lB0);
        asm volatile("s_waitcnt vmcnt(0)" ::: "memory");
        __syncthreads();
        if (kt < 3) stage(lA0, lB0, kk + 128);
        compute(lA1, lB1);
        asm volatile("s_waitcnt vmcnt(0)" ::: "memory");
        __syncthreads();
    }

    if (qk) {
        // row = o = o0 + wc*64 + ni*16 + l4*4 + j ; col = t = t0 + wr*64 + mi*16 + l15
        half_t* dstbase = (o0 < 512) ? qT : kT;
        for (int ni = 0; ni < 4; ni++) {
            int obase = o0 + wc * 64 + ni * 16 + l4 * 4;
            int hh = (obase >> 6) & 7;
            int d0 = obase & 63;
            float4_t b4 = *(const float4_t*)(qkv_b + obase);
            half_t* dst = dstbase + ((size_t)(b * 8 + hh) * 1024) * 64 + d0;
            for (int mi = 0; mi < 4; mi++) {
                int t = t0 + wr * 64 + mi * 16 + l15;
                half4_t hv;
                for (int j = 0; j < 4; j++) hv[j] = (half_t)(acc[ni][mi][j] + b4[j]);
                *(half4_t*)(dst + (size_t)t * 64) = hv;
            }
        }
    } else {
        for (int ni = 0; ni < 4; ni++) {
            int oa = o0 + wc * 64 + ni * 16 + l15;       // absolute o
            float bias = qkv_b[oa];
            int ov = oa - 1024;
            for (int mi = 0; mi < 4; mi++) {
                int t = t0 + wr * 64 + mi * 16 + l4 * 4;
                half4_t hv;
                for (int j = 0; j < 4; j++) hv[j] = (half_t)(acc[mi][ni][j] + bias);
                *(half4_t*)(vg + ((size_t)(b * 512) + ov) * 1024 + t) = hv;
            }
        }
    }
}

// ---------------- K4: flash attention per (b,h,t-tile of 64), XCD-swizzled, LAGGED-MAX ----------------
// P computed with previous m_ (no wait on current tile's cross-lane max); the max
// reduce + rare rescale run AFTER the PV MFMAs, overlapping the vmcnt/barrier wait.
__global__ __launch_bounds__(256, 4) void k_attn(const half_t* __restrict__ qT,
                                                 const half_t* __restrict__ kT,
                                                 const half_t* __restrict__ vg,
                                                 half_t* __restrict__ aT) {
    int bx = blockIdx.x;            // 2048
    // T1: all 16 t-tiles of one (b,h) on the same XCD (K/V L2-resident)
    int xcd = bx & 7, sfl = bx >> 3;          // sfl 0..255
    int bh = xcd + ((sfl >> 4) << 3);         // 0..127
    int t0 = (sfl & 15) * 64;
    int b = bh >> 3, h = bh & 7;
    const half_t* kbase = kT + (size_t)bh * 1024 * 64;                // [s][d]
    const half_t* vbase = vg + ((size_t)(b * 512 + h * 64)) * 1024;  // [d][t]

    __shared__ half_t lK0[64 * 64], lK1[64 * 64];
    __shared__ half_t lV0[64 * 64], lV1[64 * 64];
    __shared__ half_t smp[4][16 * 64];   // per-wave P[t][s], swizzled

    int tid = threadIdx.x;
    int lane = tid & 63, w = tid >> 6;
    int l15 = lane & 15, l4 = lane >> 4;
    const float SC = 0.18033688f;        // 0.125 * log2(e)

    int srow = tid >> 3;                 // 0..31
    int cs = (tid & 7) ^ (srow & 7);     // pre-swizzled source chunk

    auto stage = [&](half_t* K, half_t* V, int s0) {
        #pragma unroll
        for (int rr = 0; rr < 2; rr++) {
            int row = rr * 32 + srow;
            gload16(kbase + (size_t)(s0 + row) * 64 + cs * 8, &K[(rr * 256 + w * 64) * 8]);
            gload16(vbase + (size_t)row * 1024 + s0 + cs * 8, &V[(rr * 256 + w * 64) * 8]);
        }
    };

    // Q B-frags direct from global (pre-scaled into exp2 domain)
    half8_t bq[2];
    {
        const half_t* qrow = qT + ((size_t)bh * 1024 + t0 + w * 16 + l15) * 64;
        for (int ks = 0; ks < 2; ks++) {
            half8_t raw = *(const half8_t*)(qrow + ks * 32 + l4 * 8);
            for (int j = 0; j < 8; j++) bq[ks][j] = (half_t)((float)raw[j] * SC);
        }
    }
    half8_t aone;
    #pragma unroll
    for (int j = 0; j < 8; j++) aone[j] = (half_t)1.0f;

    half_t* pw = smp[w];
    f32x4 oacc[4] = {};
    f32x4 lacc = {};
    float m_ = 0.f;                      // lagged running max (exp2 domain), bias-init into MFMA C

    auto do_iter = [&](int it, half_t* Kc, half_t* Vc, half_t* Kn, half_t* Vn, bool pf) {
        if (pf) stage(Kn, Vn, (it + 1) * 64);
        // S^T tile biased by -m_: st = S2 - m_  (C-init = -m_)
        f32x4 st[4];
        #pragma unroll
        for (int ni = 0; ni < 4; ni++)
            for (int rr = 0; rr < 4; rr++) st[ni][rr] = -m_;
        __builtin_amdgcn_s_setprio(1);
        #pragma unroll
        for (int ks = 0; ks < 2; ks++) {
            int colk = ks * 32 + l4 * 8;
            #pragma unroll
            for (int ni = 0; ni < 4; ni++) {
                half8_t ak = *(const half8_t*)swz(Kc, ni * 16 + l15, colk);
                st[ni] = __builtin_amdgcn_mfma_f32_16x16x32_f16(ak, bq[ks], st[ni], 0, 0, 0);
            }
        }
        __builtin_amdgcn_s_setprio(0);
        // LAGGED MAX: exp2/pack/store immediately with current m_ (no cross-lane wait).
        #pragma unroll
        for (int ni = 0; ni < 4; ni++) {
            float p0 = exp2f(st[ni][0]), p1 = exp2f(st[ni][1]);
            float p2 = exp2f(st[ni][2]), p3 = exp2f(st[ni][3]);
            half2_t lo = pk16(p0, p1);
            half2_t hi = pk16(p2, p3);
            half4_t ph = {lo[0], lo[1], hi[0], hi[1]};
            *(half4_t*)swz(pw, l15, ni * 16 + l4 * 4) = ph;   // P[t][s]
        }
        // local biased tile max (independent chain; interleaves with exp2/PV issue)
        float t0m = fmaxf(fmaxf(st[0][0], st[0][1]), st[0][2]);
        float t1m = fmaxf(fmaxf(st[0][3], st[1][0]), st[1][1]);
        float t2m = fmaxf(fmaxf(st[1][2], st[1][3]), st[2][0]);
        float t3m = fmaxf(fmaxf(st[2][1], st[2][2]), st[2][3]);
        float t4m = fmaxf(fmaxf(st[3][0], st[3][1]), st[3][2]);
        float tm  = fmaxf(fmaxf(fmaxf(t0m, t1m), fmaxf(t2m, t3m)), fmaxf(t4m, st[3][3]));
        // O += V P^T ; l += 1 P^T  (A = V[d][s] / ones, B[k=s][col=t] = P rows)
        __builtin_amdgcn_s_setprio(1);
        #pragma unroll
        for (int ks = 0; ks < 2; ks++) {
            int colk = ks * 32 + l4 * 8;
            half8_t bp = *(const half8_t*)swz(pw, l15, colk);
            #pragma unroll
            for (int mi = 0; mi < 4; mi++) {
                half8_t av = *(const half8_t*)swz(Vc, mi * 16 + l15, colk);
                oacc[mi] = __builtin_amdgcn_mfma_f32_16x16x32_f16(av, bp, oacc[mi], 0, 0, 0);
            }
            lacc = __builtin_amdgcn_mfma_f32_16x16x32_f16(aone, bp, lacc, 0, 0, 0);
        }
        __builtin_amdgcn_s_setprio(0);
        // deferred max update (overlaps the vmcnt wait; rescale fires ~never for sane data)
        tm = fmaxf(tm, __shfl_xor(tm, 16, 64));
        tm = fmaxf(tm, __shfl_xor(tm, 32, 64));
        if (__any(tm > 8.0f)) {
            float d = fmaxf(tm, 0.f);
            float f = exp2f(-d);
            #pragma unroll
            for (int i = 0; i < 4; i++) lacc[i] *= f;
            #pragma unroll
            for (int mi = 0; mi < 4; mi++)
                for (int i = 0; i < 4; i++) oacc[mi][i] *= f;
            m_ += d;
        }
        asm volatile("s_waitcnt vmcnt(0)" ::: "memory");   // prefetch landed
        __syncthreads();                                   // publish; all waves done with cur
    };

    stage(lK0, lV0, 0);
    asm volatile("s_waitcnt vmcnt(0)" ::: "memory");
    __syncthreads();

    for (int hh = 0; hh < 8; hh++) {
        do_iter(2 * hh,     lK0, lV0, lK1, lV1, true);
        do_iter(2 * hh + 1, lK1, lV1, lK0, lV0, hh < 7);
    }

    // O /= l ; store aT[b][t][h*64+d]  (col t = l15 lane-local, rows d = mi*16+l4*4+i)
    float linv = 1.0f / lacc[0];
    int t = t0 + w * 16 + l15;
    for (int mi = 0; mi < 4; mi++) {
        half4_t hv;
        for (int i = 0; i < 4; i++) hv[i] = (half_t)(oacc[mi][i] * linv);
        *(half4_t*)(aT + ((size_t)(b * 1024) + t) * 512 + h * 64 + mi * 16 + l4 * 4) = hv;
    }
}

// ---------------- K5: proj GEMM + bias + residual (M=16384 flat, BM=256, BN=128), XCD-swizzled ------
__global__ __launch_bounds__(512) void k_proj_gemm(const half_t* __restrict__ aT,
                                                   const half_t* __restrict__ pw16,
                                                   const float* __restrict__ proj_b,
                                                   const float* __restrict__ x,
                                                   float* __restrict__ out) {
    int bx = blockIdx.x;            // 256 = 64 mt * 4 nt
    int xcd = bx & 7, sfl = bx >> 3;           // 0..31
    int mt = xcd + ((sfl >> 2) << 3);
    int nt = sfl & 3;
    int o0 = nt * 128;
    int b = mt >> 2;
    int t0 = (mt & 3) * 256;
    __shared__ half_t lA0[256 * 64], lA1[256 * 64];
    __shared__ half_t lB0[128 * 64], lB1[128 * 64];
    int tid = threadIdx.x;
    int lane = tid & 63, w = tid >> 6;
    int wr = w >> 1, wc = w & 1;
    int l15 = lane & 15, l4 = lane >> 4;
    int srow = lane >> 3;
    int cs = (lane & 7) ^ srow;
    const half_t* gA = aT + (size_t)mt * 256 * 512;
    const half_t* gB = pw16 + (size_t)o0 * 512;
    f32x4 acc[4][4] = {};

    auto stage = [&](half_t* LA, half_t* LB, int kk) {
        #pragma unroll
        for (int p = 0; p < 4; p++) {
            int row = w * 32 + p * 8;
            gload16(gA + (size_t)(row + srow) * 512 + kk + cs * 8, &LA[row * 64]);
        }
        #pragma unroll
        for (int p = 0; p < 2; p++) {
            int row = w * 16 + p * 8;
            gload16(gB + (size_t)(row + srow) * 512 + kk + cs * 8, &LB[row * 64]);
        }
    };
    auto compute = [&](half_t* LA, half_t* LB) {
        #pragma unroll
        for (int ks = 0; ks < 2; ks++) {
            int colk = ks * 32 + l4 * 8;
            half8_t a[4], bb[4];
            #pragma unroll
            for (int mi = 0; mi < 4; mi++) a[mi]  = *(const half8_t*)swz(LA, wr * 64 + mi * 16 + l15, colk);
            #pragma unroll
            for (int ni = 0; ni < 4; ni++) bb[ni] = *(const half8_t*)swz(LB, wc * 64 + ni * 16 + l15, colk);
            __builtin_amdgcn_s_setprio(1);
            #pragma unroll
            for (int mi = 0; mi < 4; mi++)
                #pragma unroll
                for (int ni = 0; ni < 4; ni++)
                    acc[mi][ni] = __builtin_amdgcn_mfma_f32_16x16x32_f16(a[mi], bb[ni], acc[mi][ni], 0, 0, 0);
            __builtin_amdgcn_s_setprio(0);
        }
    };

    stage(lA0, lB0, 0);
    asm volatile("s_waitcnt vmcnt(0)" ::: "memory");
    __syncthreads();
    #pragma unroll
    for (int kt = 0; kt < 4; kt++) {
        int kk = kt * 128;
        stage(lA1, lB1, kk + 64);
        compute(lA0, lB0);
        asm volatile("s_waitcnt vmcnt(0)" ::: "memory");
        __syncthreads();
        if (kt < 3) stage(lA0, lB0, kk + 128);
        compute(lA1, lB1);
        asm volatile("s_waitcnt vmcnt(0)" ::: "memory");
        __syncthreads();
    }

    for (int ni = 0; ni < 4; ni++) {
        int o = o0 + wc * 64 + ni * 16 + l15;
        float bias = proj_b[o];
        for (int mi = 0; mi < 4; mi++) {
            int t = t0 + wr * 64 + mi * 16 + l4 * 4;
            size_t idx = ((size_t)(b * 512) + o) * 1024 + t;
            float4_t xres = *(const float4_t*)(x + idx);
            float4_t ov;
            for (int j = 0; j < 4; j++) ov[j] = acc[mi][ni][j] + bias + xres[j];
            *(float4_t*)(out + idx) = ov;
        }
    }
}

extern "C" void kernel_launch(void* const* d_in, const int* in_sizes, int n_in,
                              void* d_out, int out_size, void* d_ws, size_t ws_size,
                              hipStream_t stream) {
    const float* x        = (const float*)d_in[0];
    const float* gn_scale = (const float*)d_in[1];
    const float* gn_bias  = (const float*)d_in[2];
    const float* qkv_w    = (const float*)d_in[3];
    const float* qkv_b    = (const float*)d_in[4];
    const float* proj_w   = (const float*)d_in[5];
    const float* proj_b   = (const float*)d_in[6];
    float* out = (float*)d_out;

    char* ws = (char*)d_ws;
    half_t* w16  = (half_t*)(ws + OFF_W16);
    half_t* pw16 = (half_t*)(ws + OFF_PW16);
    half_t* xnG  = (half_t*)(ws + OFF_XNG);
    half_t* qTp  = (half_t*)(ws + OFF_QT);
    half_t* kTp  = (half_t*)(ws + OFF_KT);
    half_t* vp   = (half_t*)(ws + OFF_V);
    half_t* aT   = (half_t*)(ws + OFF_AT);

    k_convert_w<<<1024, 256, 0, stream>>>(qkv_w, proj_w, w16, pw16);
    k_gn_fused<<<512, 256, 0, stream>>>(x, gn_scale, gn_bias, xnG);
    k_qkv_gemm<<<768, 512, 0, stream>>>(xnG, w16, qkv_b, qTp, kTp, vp);
    k_attn<<<2048, 256, 0, stream>>>(qTp, kTp, vp, aT);
    k_proj_gemm<<<256, 512, 0, stream>>>(aT, pw16, proj_b, x, out);
}